// Round 2
// baseline (668.649 us; speedup 1.0000x reference)
//
#include <hip/hip_runtime.h>
#include <math.h>

// Problem constants (fixed by the reference).
#define BQ   16384
#define FQ   64
#define NBQ  64
#define HD   128
#define FG   4       // feature groups
#define FPG  16      // features per group
#define MT   128     // batch rows per block
#define NT   512     // threads (8 waves)

typedef __attribute__((ext_vector_type(8))) short s16x8;   // 8 bf16 (4 VGPRs)
typedef __attribute__((ext_vector_type(4))) float f32x4;   // MFMA C/D

// round-to-nearest-even fp32 -> bf16 (weight prep only)
__device__ __forceinline__ unsigned short f2bf(float x) {
    unsigned int u = __float_as_uint(x);
    return (unsigned short)((u + 0x7FFFu + ((u >> 16) & 1u)) >> 16);
}

// pack 2 f32 -> 2 bf16 (RNE), lo from first arg
__device__ __forceinline__ unsigned cvtpk_bf16(float lo, float hi) {
    unsigned r;
    asm("v_cvt_pk_bf16_f32 %0, %1, %2" : "=v"(r) : "v"(lo), "v"(hi));
    return r;
}

__device__ __forceinline__ float softplus_stable(float v) {
    return (v > 0.0f) ? (v + log1pf(expf(-v))) : log1pf(expf(v));
}

// tanh-form gelu as sigmoid: gelu(v) = v / (1 + exp(-(1.5957691 v + 0.07135481 v^3)))
__device__ __forceinline__ f32x4 gelu4(f32x4 v) {
    const f32x4 v2 = v * v;
    const f32x4 tt = v2 * (-0.07135481f) + (-1.5957691f);
    const f32x4 s  = v * tt;
    f32x4 r;
    r[0] = __fdividef(v[0], 1.0f + __expf(s[0]));
    r[1] = __fdividef(v[1], 1.0f + __expf(s[1]));
    r[2] = __fdividef(v[2], 1.0f + __expf(s[2]));
    r[3] = __fdividef(v[3], 1.0f + __expf(s[3]));
    return r;
}

// async 16B global->LDS (LDS dest wave-uniform base + lane*16)
__device__ __forceinline__ void load16_lds(const unsigned short* g, unsigned short* l) {
    __builtin_amdgcn_global_load_lds(
        (const __attribute__((address_space(1))) unsigned int*)(uintptr_t)g,
        (__attribute__((address_space(3))) unsigned int*)(uintptr_t)l,
        16, 0, 0);
}

// h-dim permutation: C-tile (nt, row r=4q+i) -> h = 32*(nt>>1) + 8*q + 4*(nt&1) + i.
// Chosen so lane (q) holds exactly h in {8q..8q+7} (mod 32): GEMM2's B-fragment
// k = 32c + 8q + j is then IN-LANE (u[4c..4c+3]) -- no cross-lane transpose at all.

// ---------------- prep A: softmax + rbf coeffs + folded head bias + LN packs ----
// Pk layout (per (f, hg), hg = h>>2, 6 float4s = 96B):
//   [b1(4h), g1(4h), be1(4h), b2(4h), g2(4h), be2(4h)]
__global__ void __launch_bounds__(256) prep_misc(
    const float* __restrict__ att, const float* __restrict__ log_widths,
    const float* __restrict__ centers, const float* __restrict__ br,
    const float* __restrict__ bias,
    const float* __restrict__ b1, const float* __restrict__ g1, const float* __restrict__ be1,
    const float* __restrict__ b2, const float* __restrict__ g2, const float* __restrict__ be2,
    float* __restrict__ wsoft, float* __restrict__ crw2, float* __restrict__ rbias,
    float* __restrict__ Pk)
{
    const int t = threadIdx.x;
    if (blockIdx.x == 0) {
        __shared__ float ws[64];
        if (t < 64) {
            float v = att[t];
            float m = v;
#pragma unroll
            for (int s = 32; s >= 1; s >>= 1) m = fmaxf(m, __shfl_xor(m, s, 64));
            float e = expf(v - m);
            float ssum = e;
#pragma unroll
            for (int s = 32; s >= 1; s >>= 1) ssum += __shfl_xor(ssum, s, 64);
            const float w = e / ssum;
            ws[t] = w;
            wsoft[t] = w;
        }
        __syncthreads();
        for (int i = t; i < FQ * NBQ; i += 256) {
            float lw = fminf(fmaxf(log_widths[i], -5.0f), 5.0f);
            const float rw = 1.0f / (expf(lw) + 0.1f);
            ((float2*)crw2)[i] = make_float2(rw, -centers[i] * rw);
        }
        if (t < HD) {
            float s = bias[t];
            for (int f = 0; f < FQ; ++f) s += 0.1f * ws[f] * br[f * HD + t];
            rbias[t] = s;
        }
    } else {
        const int id = (blockIdx.x - 1) * 256 + t;   // id = f*32 + hg
        if (id < FQ * 32) {
            float4* dst = (float4*)Pk + (size_t)id * 6;
            dst[0] = ((const float4*)b1)[id];
            dst[1] = ((const float4*)g1)[id];
            dst[2] = ((const float4*)be1)[id];
            dst[3] = ((const float4*)b2)[id];
            dst[4] = ((const float4*)g2)[id];
            dst[5] = ((const float4*)be2)[id];
        }
    }
}

// ---------------- prep B: weight convert + swizzle into MFMA A-frag order ----
// A-frag for 16x16x32: lane l holds A[row = l&15][k = (l>>4)*8 + j], j=0..7.
// We store W^T as A with the sigma row-permutation on the h axis.
__global__ void __launch_bounds__(256) prep_swz(
    const float* __restrict__ W1, const float* __restrict__ Wr, const float* __restrict__ W2,
    unsigned short* __restrict__ W1s, unsigned short* __restrict__ Wrs,
    unsigned short* __restrict__ W2s)
{
    const int gid = blockIdx.x * 256 + threadIdx.x;
    const int l = gid & 63;
    const int r = l & 15;
    const int sig_base = ((r >> 2) << 3) + (r & 3);   // 8*(r>>2) + (r&3)
    if (gid < 131072) {
        // W1 / Wr: [F][64][128], K=64 -> 2 k-tiles
        const int id = gid & 65535;
        const float* W          = (gid < 65536) ? W1 : Wr;
        unsigned short* dst     = (gid < 65536) ? W1s : Wrs;
        const int c  = (id >> 6) & 1;
        const int nt = (id >> 7) & 7;
        const int f  = id >> 10;
        const int hrow = ((nt >> 1) << 5) + ((nt & 1) << 2) + sig_base;
        const float* src = W + ((size_t)(f * 64 + c * 32 + (l >> 4) * 8)) * HD + hrow;
        s16x8 o;
#pragma unroll
        for (int j = 0; j < 8; ++j) o[j] = (short)f2bf(src[(size_t)j * HD]);
        *(s16x8*)(dst + (size_t)f * 8192 + ((size_t)((nt * 2 + c) * 64 + l)) * 8) = o;
    } else {
        // W2: [F][128][128], K=128 -> 4 k-tiles (k = h1 in STANDARD order)
        const int id = gid - 131072;
        const int c  = (id >> 6) & 3;
        const int nt = (id >> 8) & 7;
        const int f  = id >> 11;
        const int hrow = ((nt >> 1) << 5) + ((nt & 1) << 2) + sig_base;
        const float* src = W2 + ((size_t)(f * 128 + c * 32 + (l >> 4) * 8)) * HD + hrow;
        s16x8 o;
#pragma unroll
        for (int j = 0; j < 8; ++j) o[j] = (short)f2bf(src[(size_t)j * HD]);
        *(s16x8*)(W2s + (size_t)f * 16384 + ((size_t)((nt * 4 + c) * 64 + l)) * 8) = o;
    }
}

// ---------------- prep C: LDS-tiled x transpose ----------------
__global__ void __launch_bounds__(256) prep_xtr(const float* __restrict__ x,
                                                float* __restrict__ xT) {
    __shared__ float tile[64][65];
    const int t  = threadIdx.x;
    const int b0 = blockIdx.x * 64;
    {
        const int row = t & 63, cg = (t >> 6) * 16;
        const float4* src = (const float4*)(x + (size_t)(b0 + row) * FQ + cg);
#pragma unroll
        for (int i = 0; i < 4; ++i) {
            const float4 v = src[i];
            tile[row][cg + i * 4 + 0] = v.x;
            tile[row][cg + i * 4 + 1] = v.y;
            tile[row][cg + i * 4 + 2] = v.z;
            tile[row][cg + i * 4 + 3] = v.w;
        }
    }
    __syncthreads();
    {
        const int f = t >> 2, r0 = (t & 3) * 16;
        float* dst = xT + (size_t)f * BQ + b0 + r0;
#pragma unroll
        for (int i = 0; i < 16; ++i) dst[i] = tile[r0 + i][f];
    }
}

// ---------------- fused MFMA NAM body (swapped-operand, all-register middle) ----
// grid 512 = 4 fgroups x 128 row-tiles. 512 threads = 8 waves, 16 batch cols/wave.
// C layout: lane holds batch col n = ln&15, h rows via sigma. LDS = 2 x 32KB
// double-buffered weight staging (bufA: W1+Wr, bufB: W2); no activation LDS.
__global__ void __launch_bounds__(NT, 4) nam_main(
    const float* __restrict__ crw2,
    const float* __restrict__ xT,
    const unsigned short* __restrict__ W1s,
    const unsigned short* __restrict__ Wrs,
    const unsigned short* __restrict__ W2s,
    const float* __restrict__ Pk,
    const float* __restrict__ wsoft,
    float* __restrict__ agg)
{
    __shared__ __align__(16) unsigned short bufA[16384];   // 32 KB: W1 + Wr
    __shared__ __align__(16) unsigned short bufB[16384];   // 32 KB: W2

    const int t  = threadIdx.x;
    const int ln = t & 63;
    const int wv = t >> 6;
    const int n  = ln & 15;
    const int q  = ln >> 4;
    const int fb = ln * 8;               // lane frag base (shorts)
    const int fg = blockIdx.x & 3;       // XCD-friendly: each XCD sees one fg
    const int rb = blockIdx.x >> 2;
    const int b0 = rb * MT;

    f32x4 acc[8];
#pragma unroll
    for (int nt = 0; nt < 8; ++nt) acc[nt] = f32x4{0.f, 0.f, 0.f, 0.f};

    // ---- prologue: stage f(0) weights ----
    {
        const int f0 = fg * FPG + (rb & (FPG - 1));
        const unsigned short* gw1 = W1s + (size_t)f0 * 8192;
        const unsigned short* gwr = Wrs + (size_t)f0 * 8192;
        const unsigned short* gw2 = W2s + (size_t)f0 * 16384;
#pragma unroll
        for (int i = 0; i < 4; ++i) {
            const int chunk = i * 8 + wv;
            const unsigned short* s1 = (chunk < 16) ? (gw1 + chunk * 512)
                                                    : (gwr + (chunk - 16) * 512);
            load16_lds(s1 + fb, bufA + chunk * 512);
        }
#pragma unroll
        for (int i = 0; i < 4; ++i) {
            const int chunk = i * 8 + wv;
            load16_lds(gw2 + chunk * 512 + fb, bufB + chunk * 512);
        }
    }

    for (int ff = 0; ff < FPG; ++ff) {
        const int f  = fg * FPG + ((ff + rb) & (FPG - 1));       // decorrelated order
        const int fn = fg * FPG + ((ff + 1 + rb) & (FPG - 1));
        const float wf   = wsoft[f];
        const float wf01 = 0.1f * wf;

        // ---- rbf B-fragments directly in registers ----
        // lane supplies B[k = bucket q*8+j][col = batch n] (a0: k 0..31, a1: 32..63)
        s16x8 a0, a1;
        {
            float xv = xT[(size_t)f * BQ + b0 + wv * 16 + n];
            xv = fminf(fmaxf(xv, -10.0f), 10.0f);
            const float4* c4 = ((const float4*)crw2) + f * 32;
            unsigned p[8];
#pragma unroll
            for (int h = 0; h < 2; ++h) {
#pragma unroll
                for (int i = 0; i < 4; ++i) {
                    const float4 cc = c4[h * 16 + q * 4 + i];   // {rw,nc, rw,nc}
                    const float d0 = fmaf(xv, cc.x, cc.y);
                    const float d1 = fmaf(xv, cc.z, cc.w);
                    const float e0 = __expf(-0.5f * d0 * d0);
                    const float e1 = __expf(-0.5f * d1 * d1);
                    p[h * 4 + i] = __builtin_amdgcn_perm(__float_as_uint(e1),
                                                         __float_as_uint(e0), 0x07060302u);
                }
            }
            int4 pa = make_int4(p[0], p[1], p[2], p[3]);
            int4 pb = make_int4(p[4], p[5], p[6], p[7]);
            a0 = *(s16x8*)&pa;
            a1 = *(s16x8*)&pb;
        }

        // C: full drain (vmcnt0) -> bufA(f) + bufB(f) visible. The DMA issued last
        // iteration had GEMM2+LN2+rbf of cover.
        __syncthreads();

        // ---- GEMM1 (hc) + GEMMr folded straight into acc ----
        f32x4 hc[8];
#pragma unroll
        for (int nt = 0; nt < 8; ++nt) {
            const s16x8 w10 = *(const s16x8*)&bufA[(nt * 2 + 0) * 512 + fb];
            const s16x8 w11 = *(const s16x8*)&bufA[(nt * 2 + 1) * 512 + fb];
            f32x4 z = f32x4{0.f, 0.f, 0.f, 0.f};
            z = __builtin_amdgcn_mfma_f32_16x16x32_bf16(w10, a0, z, 0, 0, 0);
            z = __builtin_amdgcn_mfma_f32_16x16x32_bf16(w11, a1, z, 0, 0, 0);
            hc[nt] = z;
            const s16x8 wr0 = *(const s16x8*)&bufA[8192 + (nt * 2 + 0) * 512 + fb];
            const s16x8 wr1 = *(const s16x8*)&bufA[8192 + (nt * 2 + 1) * 512 + fb];
            f32x4 y = f32x4{0.f, 0.f, 0.f, 0.f};
            y = __builtin_amdgcn_mfma_f32_16x16x32_bf16(wr0, a0, y, 0, 0, 0);
            y = __builtin_amdgcn_mfma_f32_16x16x32_bf16(wr1, a1, y, 0, 0, 0);
            acc[nt] = y * wf01 + acc[nt];   // residual folded now
        }

        // ---- LN1 pass 1: bias + stats (scalar per lane; h axis is in-lane + q) ----
        const float4* pkf = (const float4*)Pk + (size_t)f * 192 + q * 12;
        f32x4 sm4 = {0.f, 0.f, 0.f, 0.f}, sq4 = {0.f, 0.f, 0.f, 0.f};
#pragma unroll
        for (int nt = 0; nt < 8; ++nt) {
            const f32x4 bg = *(const f32x4*)(pkf + (nt >> 1) * 48 + (nt & 1) * 6);
            const f32x4 v = hc[nt] + bg;
            hc[nt] = v; sm4 += v; sq4 += v * v;
        }
        float sm = (sm4[0] + sm4[1]) + (sm4[2] + sm4[3]);
        float sq = (sq4[0] + sq4[1]) + (sq4[2] + sq4[3]);
        sm += __shfl_xor(sm, 16); sm += __shfl_xor(sm, 32);
        sq += __shfl_xor(sq, 16); sq += __shfl_xor(sq, 32);
        const float mu = sm * (1.0f / 128.0f);
        const float rs = rsqrtf(sq * (1.0f / 128.0f) - mu * mu + 1e-5f);

        // E: bufA readers done (all waves past GEMM1); trivial vmcnt drain.
        __syncthreads();

        // ---- stage W1+Wr(fn) -> bufA; stays in flight across H, drained at next C ----
        if (ff < FPG - 1) {
            const unsigned short* gw1 = W1s + (size_t)fn * 8192;
            const unsigned short* gwr = Wrs + (size_t)fn * 8192;
#pragma unroll
            for (int i = 0; i < 4; ++i) {
                const int chunk = i * 8 + wv;
                const unsigned short* s1 = (chunk < 16) ? (gw1 + chunk * 512)
                                                        : (gwr + (chunk - 16) * 512);
                load16_lds(s1 + fb, bufA + chunk * 512);
            }
        }

        // ---- LN1 pass 2 + gelu + pack: sigma makes GEMM2 B-frags IN-LANE ----
        unsigned u[16];
#pragma unroll
        for (int nt = 0; nt < 8; ++nt) {
            const f32x4 gg = *(const f32x4*)(pkf + (nt >> 1) * 48 + (nt & 1) * 6 + 1);
            const f32x4 bb = *(const f32x4*)(pkf + (nt >> 1) * 48 + (nt & 1) * 6 + 2);
            const f32x4 y = (hc[nt] - mu) * (gg * rs) + bb;
            const f32x4 z = gelu4(y);
            u[nt * 2 + 0] = cvtpk_bf16(z[0], z[1]);
            u[nt * 2 + 1] = cvtpk_bf16(z[2], z[3]);
        }
        s16x8 bfr[4];
#pragma unroll
        for (int c = 0; c < 4; ++c) {
            int4 w = make_int4(u[4 * c], u[4 * c + 1], u[4 * c + 2], u[4 * c + 3]);
            bfr[c] = *(s16x8*)&w;
        }

        // ---- GEMM2: A = W2 frags (LDS), B = bfr (registers, K=128) ----
        f32x4 h2[8];
#pragma unroll
        for (int nt = 0; nt < 8; ++nt) {
            f32x4 z = f32x4{0.f, 0.f, 0.f, 0.f};
#pragma unroll
            for (int c = 0; c < 4; ++c) {
                const s16x8 w2f = *(const s16x8*)&bufB[(nt * 4 + c) * 512 + fb];
                z = __builtin_amdgcn_mfma_f32_16x16x32_bf16(w2f, bfr[c], z, 0, 0, 0);
            }
            h2[nt] = z;
        }

        // H: raw barrier -- bufB readers done; W1Wr(fn) DMA deliberately crosses.
        __builtin_amdgcn_sched_barrier(0);
        __builtin_amdgcn_s_barrier();
        __builtin_amdgcn_sched_barrier(0);

        // ---- stage W2(fn) -> bufB; covered by LN2 + next rbf, drained at next C ----
        if (ff < FPG - 1) {
            const unsigned short* gw2 = W2s + (size_t)fn * 16384;
#pragma unroll
            for (int i = 0; i < 4; ++i) {
                const int chunk = i * 8 + wv;
                load16_lds(gw2 + chunk * 512 + fb, bufB + chunk * 512);
            }
        }

        // ---- LN2 (+b2), gelu, attention weight into acc ----
        f32x4 tm4 = {0.f, 0.f, 0.f, 0.f}, tq4 = {0.f, 0.f, 0.f, 0.f};
#pragma unroll
        for (int nt = 0; nt < 8; ++nt) {
            const f32x4 bg = *(const f32x4*)(pkf + (nt >> 1) * 48 + (nt & 1) * 6 + 3);
            const f32x4 v = h2[nt] + bg;
            h2[nt] = v; tm4 += v; tq4 += v * v;
        }
        float tm = (tm4[0] + tm4[1]) + (tm4[2] + tm4[3]);
        float tq = (tq4[0] + tq4[1]) + (tq4[2] + tq4[3]);
        tm += __shfl_xor(tm, 16); tm += __shfl_xor(tm, 32);
        tq += __shfl_xor(tq, 16); tq += __shfl_xor(tq, 32);
        const float mu2 = tm * (1.0f / 128.0f);
        const float rs2 = rsqrtf(tq * (1.0f / 128.0f) - mu2 * mu2 + 1e-5f);
#pragma unroll
        for (int nt = 0; nt < 8; ++nt) {
            const f32x4 gg = *(const f32x4*)(pkf + (nt >> 1) * 48 + (nt & 1) * 6 + 4);
            const f32x4 bb = *(const f32x4*)(pkf + (nt >> 1) * 48 + (nt & 1) * 6 + 5);
            const f32x4 y = (h2[nt] - mu2) * (gg * rs2) + bb;
            acc[nt] = gelu4(y) * wf + acc[nt];
        }
    }

    // ---- epilogue: atomic accumulate into agg; col = sigma(nt, 4q+i) ----
    float* ap = agg + (size_t)(b0 + wv * 16 + n) * HD + q * 8;
#pragma unroll
    for (int nt = 0; nt < 8; ++nt) {
#pragma unroll
        for (int i = 0; i < 4; ++i) {
            atomicAdd(ap + ((nt >> 1) << 5) + ((nt & 1) << 2) + i, acc[nt][i]);
        }
    }
}

// ---------------- mixture-beta head: one wave per batch row ----------------
__global__ void __launch_bounds__(256) nam_head(
    const float* __restrict__ agg, const float* __restrict__ rbias,
    const float* __restrict__ Wpi, const float* __restrict__ bpi,
    const float* __restrict__ Wa,  const float* __restrict__ ba,
    const float* __restrict__ Wb,  const float* __restrict__ bb,
    float* __restrict__ out)
{
    const int gid  = blockIdx.x * blockDim.x + threadIdx.x;
    const int row  = gid >> 6;
    const int lane = threadIdx.x & 63;
    if (row >= BQ) return;

    const float2 p  = ((const float2*)(agg + (size_t)row * HD))[lane];
    const float2 rb = ((const float2*)rbias)[lane];
    const float ax = p.x + rb.x;
    const float ay = p.y + rb.y;

    const float2* wp = (const float2*)Wpi;
    const float2* wa = (const float2*)Wa;
    const float2* wb = (const float2*)Wb;
    const float2 p01 = wp[lane * 3], p23 = wp[lane * 3 + 1], p45 = wp[lane * 3 + 2];
    const float2 a01 = wa[lane * 3], a23 = wa[lane * 3 + 1], a45 = wa[lane * 3 + 2];
    const float2 b01 = wb[lane * 3], b23 = wb[lane * 3 + 1], b45 = wb[lane * 3 + 2];

    float ppi0 = ax * p01.x + ay * p23.y;
    float ppi1 = ax * p01.y + ay * p45.x;
    float ppi2 = ax * p23.x + ay * p45.y;
    float pa0  = ax * a01.x + ay * a23.y;
    float pa1  = ax * a01.y + ay * a45.x;
    float pa2  = ax * a23.x + ay * a45.y;
    float pb0  = ax * b01.x + ay * b23.y;
    float pb1  = ax * b01.y + ay * b45.x;
    float pb2  = ax * b23.x + ay * b45.y;

#pragma unroll
    for (int s = 32; s >= 1; s >>= 1) {
        ppi0 += __shfl_xor(ppi0, s, 64);
        ppi1 += __shfl_xor(ppi1, s, 64);
        ppi2 += __shfl_xor(ppi2, s, 64);
        pa0  += __shfl_xor(pa0,  s, 64);
        pa1  += __shfl_xor(pa1,  s, 64);
        pa2  += __shfl_xor(pa2,  s, 64);
        pb0  += __shfl_xor(pb0,  s, 64);
        pb1  += __shfl_xor(pb1,  s, 64);
        pb2  += __shfl_xor(pb2,  s, 64);
    }

    if (lane == 0) {
        const float z0 = ppi0 + bpi[0], z1 = ppi1 + bpi[1], z2 = ppi2 + bpi[2];
        const float mz = fmaxf(z0, fmaxf(z1, z2));
        const float e0 = expf(z0 - mz), e1 = expf(z1 - mz), e2 = expf(z2 - mz);
        const float es = e0 + e1 + e2;

        const float al0 = fminf(fmaxf(softplus_stable(pa0 + ba[0]) + 1.01f, 1.01f), 100.0f);
        const float al1 = fminf(fmaxf(softplus_stable(pa1 + ba[1]) + 1.01f, 1.01f), 100.0f);
        const float al2 = fminf(fmaxf(softplus_stable(pa2 + ba[2]) + 1.01f, 1.01f), 100.0f);
        const float bt0 = fminf(fmaxf(softplus_stable(pb0 + bb[0]) + 1.01f, 1.01f), 100.0f);
        const float bt1 = fminf(fmaxf(softplus_stable(pb1 + bb[1]) + 1.01f, 1.01f), 100.0f);
        const float bt2 = fminf(fmaxf(softplus_stable(pb2 + bb[2]) + 1.01f, 1.01f), 100.0f);

        const float pred = (e0 * (al0 / (al0 + bt0))
                          + e1 * (al1 / (al1 + bt1))
                          + e2 * (al2 / (al2 + bt2))) / es;
        out[row] = fminf(fmaxf(pred, 0.001f), 0.999f);
    }
}

extern "C" void kernel_launch(void* const* d_in, const int* in_sizes, int n_in,
                              void* d_out, int out_size, void* d_ws, size_t ws_size,
                              hipStream_t stream) {
    const float* x          = (const float*)d_in[0];
    const float* centers    = (const float*)d_in[1];
    const float* log_widths = (const float*)d_in[2];
    const float* W1   = (const float*)d_in[3];
    const float* b1   = (const float*)d_in[4];
    const float* g1   = (const float*)d_in[5];
    const float* be1  = (const float*)d_in[6];
    const float* W2   = (const float*)d_in[7];
    const float* b2   = (const float*)d_in[8];
    const float* g2   = (const float*)d_in[9];
    const float* be2  = (const float*)d_in[10];
    const float* Wr   = (const float*)d_in[11];
    const float* br   = (const float*)d_in[12];
    const float* att  = (const float*)d_in[13];
    const float* bias = (const float*)d_in[14];
    const float* Wpi  = (const float*)d_in[15];
    const float* bpi  = (const float*)d_in[16];
    const float* Wa   = (const float*)d_in[17];
    const float* ba   = (const float*)d_in[18];
    const float* Wb   = (const float*)d_in[19];
    const float* bb   = (const float*)d_in[20];

    // ---- workspace layout (byte offsets, 16B-aligned) ----
    char* ws = (char*)d_ws;
    float*          wsoft = (float*)(ws + 0);          //   256 B
    float*          rbias = (float*)(ws + 1024);       //   512 B
    float*          crw2  = (float*)(ws + 8192);       //  32 KB (float2[4096])
    float*          Pk    = (float*)(ws + 65536);      // 192 KB used (of 256 KB)
    float*          xT    = (float*)(ws + 327680);     //   4 MB
    unsigned short* W1s   = (unsigned short*)(ws + 4521984);   // 1 MB
    unsigned short* Wrs   = (unsigned short*)(ws + 5570560);   // 1 MB
    unsigned short* W2s   = (unsigned short*)(ws + 6619136);   // 2 MB
    float*          agg   = (float*)(ws + 8716288);    //   8 MB

    prep_misc<<<9, 256, 0, stream>>>(att, log_widths, centers, br, bias,
                                     b1, g1, be1, b2, g2, be2,
                                     wsoft, crw2, rbias, Pk);
    prep_swz<<<1024, 256, 0, stream>>>(W1, Wr, W2, W1s, Wrs, W2s);
    prep_xtr<<<256, 256, 0, stream>>>(x, xT);
    hipMemsetAsync(agg, 0, (size_t)BQ * HD * sizeof(float), stream);

    nam_main<<<(BQ / MT) * FG, NT, 0, stream>>>(crw2, xT, W1s, Wrs, W2s, Pk,
                                                wsoft, agg);

    nam_head<<<BQ / 4, 256, 0, stream>>>(agg, rbias, Wpi, bpi, Wa, ba, Wb, bb,
                                         (float*)d_out);
}

// Round 3
// 522.361 us; speedup vs baseline: 1.2801x; 1.2801x over previous
//
#include <hip/hip_runtime.h>
#include <math.h>

// Problem constants (fixed by the reference).
#define BQ   16384
#define FQ   64
#define NBQ  64
#define HD   128
#define FG   4       // feature groups
#define FPG  16      // features per group
#define MT   128     // batch rows per block
#define NT   512     // threads (8 waves)

typedef __attribute__((ext_vector_type(8))) short s16x8;   // 8 bf16 (4 VGPRs)
typedef __attribute__((ext_vector_type(4))) float f32x4;   // MFMA C/D

// round-to-nearest-even fp32 -> bf16 (weight prep only)
__device__ __forceinline__ unsigned short f2bf(float x) {
    unsigned int u = __float_as_uint(x);
    return (unsigned short)((u + 0x7FFFu + ((u >> 16) & 1u)) >> 16);
}

// pack 2 f32 -> 2 bf16 (RNE), lo from first arg
__device__ __forceinline__ unsigned cvtpk_bf16(float lo, float hi) {
    unsigned r;
    asm("v_cvt_pk_bf16_f32 %0, %1, %2" : "=v"(r) : "v"(lo), "v"(hi));
    return r;
}

__device__ __forceinline__ float softplus_stable(float v) {
    return (v > 0.0f) ? (v + log1pf(expf(-v))) : log1pf(expf(v));
}

// tanh-form gelu as sigmoid: gelu(v) = v / (1 + exp(-(1.5957691 v + 0.07135481 v^3)))
__device__ __forceinline__ f32x4 gelu4(f32x4 v) {
    const f32x4 v2 = v * v;
    const f32x4 tt = v2 * (-0.07135481f) + (-1.5957691f);
    const f32x4 s  = v * tt;
    f32x4 r;
    r[0] = __fdividef(v[0], 1.0f + __expf(s[0]));
    r[1] = __fdividef(v[1], 1.0f + __expf(s[1]));
    r[2] = __fdividef(v[2], 1.0f + __expf(s[2]));
    r[3] = __fdividef(v[3], 1.0f + __expf(s[3]));
    return r;
}

// async 16B global->LDS (LDS dest wave-uniform base + lane*16)
__device__ __forceinline__ void load16_lds(const unsigned short* g, unsigned short* l) {
    __builtin_amdgcn_global_load_lds(
        (const __attribute__((address_space(1))) unsigned int*)(uintptr_t)g,
        (__attribute__((address_space(3))) unsigned int*)(uintptr_t)l,
        16, 0, 0);
}

// h-dim permutation: C-tile (nt, row r=4q+i) -> h = 32*(nt>>1) + 8*q + 4*(nt&1) + i.
// Chosen so lane (q) holds exactly h in {8q..8q+7} (mod 32): GEMM2's B-fragment
// k = 32c + 8q + j is then IN-LANE (u[4c..4c+3]) -- no cross-lane transpose at all.

// ---------------- prep A: softmax + rbf coeffs + folded head bias + LN packs ----
// Pk layout (per (f, hg), hg = h>>2, 6 float4s = 96B):
//   [b1(4h), g1(4h), be1(4h), b2(4h), g2(4h), be2(4h)]
__global__ void __launch_bounds__(256) prep_misc(
    const float* __restrict__ att, const float* __restrict__ log_widths,
    const float* __restrict__ centers, const float* __restrict__ br,
    const float* __restrict__ bias,
    const float* __restrict__ b1, const float* __restrict__ g1, const float* __restrict__ be1,
    const float* __restrict__ b2, const float* __restrict__ g2, const float* __restrict__ be2,
    float* __restrict__ wsoft, float* __restrict__ crw2, float* __restrict__ rbias,
    float* __restrict__ Pk)
{
    const int t = threadIdx.x;
    if (blockIdx.x == 0) {
        __shared__ float ws[64];
        if (t < 64) {
            float v = att[t];
            float m = v;
#pragma unroll
            for (int s = 32; s >= 1; s >>= 1) m = fmaxf(m, __shfl_xor(m, s, 64));
            float e = expf(v - m);
            float ssum = e;
#pragma unroll
            for (int s = 32; s >= 1; s >>= 1) ssum += __shfl_xor(ssum, s, 64);
            const float w = e / ssum;
            ws[t] = w;
            wsoft[t] = w;
        }
        __syncthreads();
        for (int i = t; i < FQ * NBQ; i += 256) {
            float lw = fminf(fmaxf(log_widths[i], -5.0f), 5.0f);
            const float rw = 1.0f / (expf(lw) + 0.1f);
            ((float2*)crw2)[i] = make_float2(rw, -centers[i] * rw);
        }
        if (t < HD) {
            float s = bias[t];
            for (int f = 0; f < FQ; ++f) s += 0.1f * ws[f] * br[f * HD + t];
            rbias[t] = s;
        }
    } else {
        const int id = (blockIdx.x - 1) * 256 + t;   // id = f*32 + hg
        if (id < FQ * 32) {
            float4* dst = (float4*)Pk + (size_t)id * 6;
            dst[0] = ((const float4*)b1)[id];
            dst[1] = ((const float4*)g1)[id];
            dst[2] = ((const float4*)be1)[id];
            dst[3] = ((const float4*)b2)[id];
            dst[4] = ((const float4*)g2)[id];
            dst[5] = ((const float4*)be2)[id];
        }
    }
}

// ---------------- prep B: weight convert + swizzle into MFMA A-frag order ----
// A-frag for 16x16x32: lane l holds A[row = l&15][k = (l>>4)*8 + j], j=0..7.
// We store W^T as A with the sigma row-permutation on the h axis.
__global__ void __launch_bounds__(256) prep_swz(
    const float* __restrict__ W1, const float* __restrict__ Wr, const float* __restrict__ W2,
    unsigned short* __restrict__ W1s, unsigned short* __restrict__ Wrs,
    unsigned short* __restrict__ W2s)
{
    const int gid = blockIdx.x * 256 + threadIdx.x;
    const int l = gid & 63;
    const int r = l & 15;
    const int sig_base = ((r >> 2) << 3) + (r & 3);   // 8*(r>>2) + (r&3)
    if (gid < 131072) {
        // W1 / Wr: [F][64][128], K=64 -> 2 k-tiles
        const int id = gid & 65535;
        const float* W          = (gid < 65536) ? W1 : Wr;
        unsigned short* dst     = (gid < 65536) ? W1s : Wrs;
        const int c  = (id >> 6) & 1;
        const int nt = (id >> 7) & 7;
        const int f  = id >> 10;
        const int hrow = ((nt >> 1) << 5) + ((nt & 1) << 2) + sig_base;
        const float* src = W + ((size_t)(f * 64 + c * 32 + (l >> 4) * 8)) * HD + hrow;
        s16x8 o;
#pragma unroll
        for (int j = 0; j < 8; ++j) o[j] = (short)f2bf(src[(size_t)j * HD]);
        *(s16x8*)(dst + (size_t)f * 8192 + ((size_t)((nt * 2 + c) * 64 + l)) * 8) = o;
    } else {
        // W2: [F][128][128], K=128 -> 4 k-tiles (k = h1 in STANDARD order)
        const int id = gid - 131072;
        const int c  = (id >> 6) & 3;
        const int nt = (id >> 8) & 7;
        const int f  = id >> 11;
        const int hrow = ((nt >> 1) << 5) + ((nt & 1) << 2) + sig_base;
        const float* src = W2 + ((size_t)(f * 128 + c * 32 + (l >> 4) * 8)) * HD + hrow;
        s16x8 o;
#pragma unroll
        for (int j = 0; j < 8; ++j) o[j] = (short)f2bf(src[(size_t)j * HD]);
        *(s16x8*)(W2s + (size_t)f * 16384 + ((size_t)((nt * 4 + c) * 64 + l)) * 8) = o;
    }
}

// ---------------- prep C: LDS-tiled x transpose ----------------
__global__ void __launch_bounds__(256) prep_xtr(const float* __restrict__ x,
                                                float* __restrict__ xT) {
    __shared__ float tile[64][65];
    const int t  = threadIdx.x;
    const int b0 = blockIdx.x * 64;
    {
        const int row = t & 63, cg = (t >> 6) * 16;
        const float4* src = (const float4*)(x + (size_t)(b0 + row) * FQ + cg);
#pragma unroll
        for (int i = 0; i < 4; ++i) {
            const float4 v = src[i];
            tile[row][cg + i * 4 + 0] = v.x;
            tile[row][cg + i * 4 + 1] = v.y;
            tile[row][cg + i * 4 + 2] = v.z;
            tile[row][cg + i * 4 + 3] = v.w;
        }
    }
    __syncthreads();
    {
        const int f = t >> 2, r0 = (t & 3) * 16;
        float* dst = xT + (size_t)f * BQ + b0 + r0;
#pragma unroll
        for (int i = 0; i < 16; ++i) dst[i] = tile[r0 + i][f];
    }
}

// ---------------- fused MFMA NAM body (swapped-operand, all-register middle) ----
// grid 512 = 4 fgroups x 128 row-tiles. 512 threads = 8 waves, 16 batch cols/wave.
// C layout: lane holds batch col n = ln&15, h rows via sigma. LDS = 64 KB shared
// scratch: weight staging (bufA: W1+Wr, bufB: W2) in-loop; f32 128x128 tile in
// the epilogue for COALESCED atomic write-out (the round-1 regression fix).
__global__ void __launch_bounds__(NT, 4) nam_main(
    const float* __restrict__ crw2,
    const float* __restrict__ xT,
    const unsigned short* __restrict__ W1s,
    const unsigned short* __restrict__ Wrs,
    const unsigned short* __restrict__ W2s,
    const float* __restrict__ Pk,
    const float* __restrict__ wsoft,
    float* __restrict__ agg)
{
    __shared__ __align__(16) unsigned short smem[32768];   // 64 KB
    unsigned short* bufA = smem;            // 32 KB: W1 + Wr
    unsigned short* bufB = smem + 16384;    // 32 KB: W2

    const int t  = threadIdx.x;
    const int ln = t & 63;
    const int wv = t >> 6;
    const int n  = ln & 15;
    const int q  = ln >> 4;
    const int fb = ln * 8;               // lane frag base (shorts)
    const int fg = blockIdx.x & 3;
    const int rb = blockIdx.x >> 2;
    const int b0 = rb * MT;

    f32x4 acc[8];
#pragma unroll
    for (int nt = 0; nt < 8; ++nt) acc[nt] = f32x4{0.f, 0.f, 0.f, 0.f};

    // ---- prologue: stage f(0) weights ----
    {
        const int f0 = fg * FPG + (rb & (FPG - 1));
        const unsigned short* gw1 = W1s + (size_t)f0 * 8192;
        const unsigned short* gwr = Wrs + (size_t)f0 * 8192;
        const unsigned short* gw2 = W2s + (size_t)f0 * 16384;
#pragma unroll
        for (int i = 0; i < 4; ++i) {
            const int chunk = i * 8 + wv;
            const unsigned short* s1 = (chunk < 16) ? (gw1 + chunk * 512)
                                                    : (gwr + (chunk - 16) * 512);
            load16_lds(s1 + fb, bufA + chunk * 512);
        }
#pragma unroll
        for (int i = 0; i < 4; ++i) {
            const int chunk = i * 8 + wv;
            load16_lds(gw2 + chunk * 512 + fb, bufB + chunk * 512);
        }
    }

    for (int ff = 0; ff < FPG; ++ff) {
        const int f  = fg * FPG + ((ff + rb) & (FPG - 1));       // decorrelated order
        const int fn = fg * FPG + ((ff + 1 + rb) & (FPG - 1));
        const float wf   = wsoft[f];
        const float wf01 = 0.1f * wf;

        // ---- rbf B-fragments directly in registers ----
        // lane supplies B[k = bucket q*8+j][col = batch n] (a0: k 0..31, a1: 32..63)
        s16x8 a0, a1;
        {
            float xv = xT[(size_t)f * BQ + b0 + wv * 16 + n];
            xv = fminf(fmaxf(xv, -10.0f), 10.0f);
            const float4* c4 = ((const float4*)crw2) + f * 32;
            unsigned p[8];
#pragma unroll
            for (int h = 0; h < 2; ++h) {
#pragma unroll
                for (int i = 0; i < 4; ++i) {
                    const float4 cc = c4[h * 16 + q * 4 + i];   // {rw,nc, rw,nc}
                    const float d0 = fmaf(xv, cc.x, cc.y);
                    const float d1 = fmaf(xv, cc.z, cc.w);
                    const float e0 = __expf(-0.5f * d0 * d0);
                    const float e1 = __expf(-0.5f * d1 * d1);
                    p[h * 4 + i] = __builtin_amdgcn_perm(__float_as_uint(e1),
                                                         __float_as_uint(e0), 0x07060302u);
                }
            }
            int4 pa = make_int4(p[0], p[1], p[2], p[3]);
            int4 pb = make_int4(p[4], p[5], p[6], p[7]);
            a0 = *(s16x8*)&pa;
            a1 = *(s16x8*)&pb;
        }

        // C: full drain (vmcnt0) -> bufA(f) + bufB(f) visible. The DMA issued last
        // iteration had GEMM2+LN2+rbf of cover.
        __syncthreads();

        // ---- GEMM1 (hc) + GEMMr folded straight into acc ----
        f32x4 hc[8];
#pragma unroll
        for (int nt = 0; nt < 8; ++nt) {
            const s16x8 w10 = *(const s16x8*)&bufA[(nt * 2 + 0) * 512 + fb];
            const s16x8 w11 = *(const s16x8*)&bufA[(nt * 2 + 1) * 512 + fb];
            f32x4 z = f32x4{0.f, 0.f, 0.f, 0.f};
            z = __builtin_amdgcn_mfma_f32_16x16x32_bf16(w10, a0, z, 0, 0, 0);
            z = __builtin_amdgcn_mfma_f32_16x16x32_bf16(w11, a1, z, 0, 0, 0);
            hc[nt] = z;
            const s16x8 wr0 = *(const s16x8*)&bufA[8192 + (nt * 2 + 0) * 512 + fb];
            const s16x8 wr1 = *(const s16x8*)&bufA[8192 + (nt * 2 + 1) * 512 + fb];
            f32x4 y = f32x4{0.f, 0.f, 0.f, 0.f};
            y = __builtin_amdgcn_mfma_f32_16x16x32_bf16(wr0, a0, y, 0, 0, 0);
            y = __builtin_amdgcn_mfma_f32_16x16x32_bf16(wr1, a1, y, 0, 0, 0);
            acc[nt] = y * wf01 + acc[nt];   // residual folded now
        }

        // ---- LN1 pass 1: bias + stats (scalar per lane; h axis is in-lane + q) ----
        const float4* pkf = (const float4*)Pk + (size_t)f * 192 + q * 12;
        f32x4 sm4 = {0.f, 0.f, 0.f, 0.f}, sq4 = {0.f, 0.f, 0.f, 0.f};
#pragma unroll
        for (int nt = 0; nt < 8; ++nt) {
            const f32x4 bg = *(const f32x4*)(pkf + (nt >> 1) * 48 + (nt & 1) * 6);
            const f32x4 v = hc[nt] + bg;
            hc[nt] = v; sm4 += v; sq4 += v * v;
        }
        float sm = (sm4[0] + sm4[1]) + (sm4[2] + sm4[3]);
        float sq = (sq4[0] + sq4[1]) + (sq4[2] + sq4[3]);
        sm += __shfl_xor(sm, 16); sm += __shfl_xor(sm, 32);
        sq += __shfl_xor(sq, 16); sq += __shfl_xor(sq, 32);
        const float mu = sm * (1.0f / 128.0f);
        const float rs = rsqrtf(sq * (1.0f / 128.0f) - mu * mu + 1e-5f);

        // E: bufA readers done (all waves past GEMM1); trivial vmcnt drain.
        __syncthreads();

        // ---- stage W1+Wr(fn) -> bufA; stays in flight across H, drained at next C ----
        if (ff < FPG - 1) {
            const unsigned short* gw1 = W1s + (size_t)fn * 8192;
            const unsigned short* gwr = Wrs + (size_t)fn * 8192;
#pragma unroll
            for (int i = 0; i < 4; ++i) {
                const int chunk = i * 8 + wv;
                const unsigned short* s1 = (chunk < 16) ? (gw1 + chunk * 512)
                                                        : (gwr + (chunk - 16) * 512);
                load16_lds(s1 + fb, bufA + chunk * 512);
            }
        }

        // ---- LN1 pass 2 + gelu + pack: sigma makes GEMM2 B-frags IN-LANE ----
        unsigned u[16];
#pragma unroll
        for (int nt = 0; nt < 8; ++nt) {
            const f32x4 gg = *(const f32x4*)(pkf + (nt >> 1) * 48 + (nt & 1) * 6 + 1);
            const f32x4 bb = *(const f32x4*)(pkf + (nt >> 1) * 48 + (nt & 1) * 6 + 2);
            const f32x4 y = (hc[nt] - mu) * (gg * rs) + bb;
            const f32x4 z = gelu4(y);
            u[nt * 2 + 0] = cvtpk_bf16(z[0], z[1]);
            u[nt * 2 + 1] = cvtpk_bf16(z[2], z[3]);
        }
        s16x8 bfr[4];
#pragma unroll
        for (int c = 0; c < 4; ++c) {
            int4 w = make_int4(u[4 * c], u[4 * c + 1], u[4 * c + 2], u[4 * c + 3]);
            bfr[c] = *(s16x8*)&w;
        }

        // ---- GEMM2: A = W2 frags (LDS), B = bfr (registers, K=128) ----
        f32x4 h2[8];
#pragma unroll
        for (int nt = 0; nt < 8; ++nt) {
            f32x4 z = f32x4{0.f, 0.f, 0.f, 0.f};
#pragma unroll
            for (int c = 0; c < 4; ++c) {
                const s16x8 w2f = *(const s16x8*)&bufB[(nt * 4 + c) * 512 + fb];
                z = __builtin_amdgcn_mfma_f32_16x16x32_bf16(w2f, bfr[c], z, 0, 0, 0);
            }
            h2[nt] = z;
        }

        // H: raw barrier -- bufB readers done; W1Wr(fn) DMA deliberately crosses.
        __builtin_amdgcn_sched_barrier(0);
        __builtin_amdgcn_s_barrier();
        __builtin_amdgcn_sched_barrier(0);

        // ---- stage W2(fn) -> bufB; covered by LN2 + next rbf, drained at next C ----
        if (ff < FPG - 1) {
            const unsigned short* gw2 = W2s + (size_t)fn * 16384;
#pragma unroll
            for (int i = 0; i < 4; ++i) {
                const int chunk = i * 8 + wv;
                load16_lds(gw2 + chunk * 512 + fb, bufB + chunk * 512);
            }
        }

        // ---- LN2 (+b2), gelu, attention weight into acc ----
        f32x4 tm4 = {0.f, 0.f, 0.f, 0.f}, tq4 = {0.f, 0.f, 0.f, 0.f};
#pragma unroll
        for (int nt = 0; nt < 8; ++nt) {
            const f32x4 bg = *(const f32x4*)(pkf + (nt >> 1) * 48 + (nt & 1) * 6 + 3);
            const f32x4 v = h2[nt] + bg;
            h2[nt] = v; tm4 += v; tq4 += v * v;
        }
        float tm = (tm4[0] + tm4[1]) + (tm4[2] + tm4[3]);
        float tq = (tq4[0] + tq4[1]) + (tq4[2] + tq4[3]);
        tm += __shfl_xor(tm, 16); tm += __shfl_xor(tm, 32);
        tq += __shfl_xor(tq, 16); tq += __shfl_xor(tq, 32);
        const float mu2 = tm * (1.0f / 128.0f);
        const float rs2 = rsqrtf(tq * (1.0f / 128.0f) - mu2 * mu2 + 1e-5f);
#pragma unroll
        for (int nt = 0; nt < 8; ++nt) {
            const f32x4 gg = *(const f32x4*)(pkf + (nt >> 1) * 48 + (nt & 1) * 6 + 4);
            const f32x4 bb = *(const f32x4*)(pkf + (nt >> 1) * 48 + (nt & 1) * 6 + 5);
            const f32x4 y = (h2[nt] - mu2) * (gg * rs2) + bb;
            acc[nt] = gelu4(y) * wf + acc[nt];
        }
    }

    // ---- epilogue: LDS re-coalesce (128x128 f32 tile, XOR-swizzled) ----
    // All waves passed barrier H of the last iteration => no LDS readers remain,
    // no DMA in flight (last iter staged nothing). Safe to overwrite smem.
    {
        float* fs = (float*)smem;
        const int r = wv * 16 + n;               // this lane's local batch row
#pragma unroll
        for (int nt = 0; nt < 8; ++nt) {
            const int col  = ((nt >> 1) << 5) + (q << 3) + ((nt & 1) << 2);
            const int byte = r * 512 + col * 4;
            const int sw   = byte ^ ((r & 7) << 4);   // bank-spread, 16B-aligned
            *(f32x4*)((char*)fs + sw) = acc[nt];
        }
        __syncthreads();
        // wave wv drains rows [wv*16, wv*16+16); per instruction: 64 lanes hit
        // 64 CONSECUTIVE floats (256B) -> hardware-mergeable atomics.
        float* aggp = agg + (size_t)b0 * HD;
#pragma unroll
        for (int rr = 0; rr < 16; ++rr) {
            const int row = wv * 16 + rr;
#pragma unroll
            for (int half = 0; half < 2; ++half) {
                const int byte = row * 512 + half * 256 + ln * 4;
                const int sw   = byte ^ ((row & 7) << 4);
                const float v  = *(const float*)((const char*)fs + sw);
                atomicAdd(aggp + (size_t)row * HD + half * 64 + ln, v);
            }
        }
    }
}

// ---------------- mixture-beta head: one wave per batch row ----------------
__global__ void __launch_bounds__(256) nam_head(
    const float* __restrict__ agg, const float* __restrict__ rbias,
    const float* __restrict__ Wpi, const float* __restrict__ bpi,
    const float* __restrict__ Wa,  const float* __restrict__ ba,
    const float* __restrict__ Wb,  const float* __restrict__ bb,
    float* __restrict__ out)
{
    const int gid  = blockIdx.x * blockDim.x + threadIdx.x;
    const int row  = gid >> 6;
    const int lane = threadIdx.x & 63;
    if (row >= BQ) return;

    const float2 p  = ((const float2*)(agg + (size_t)row * HD))[lane];
    const float2 rb = ((const float2*)rbias)[lane];
    const float ax = p.x + rb.x;
    const float ay = p.y + rb.y;

    const float2* wp = (const float2*)Wpi;
    const float2* wa = (const float2*)Wa;
    const float2* wb = (const float2*)Wb;
    const float2 p01 = wp[lane * 3], p23 = wp[lane * 3 + 1], p45 = wp[lane * 3 + 2];
    const float2 a01 = wa[lane * 3], a23 = wa[lane * 3 + 1], a45 = wa[lane * 3 + 2];
    const float2 b01 = wb[lane * 3], b23 = wb[lane * 3 + 1], b45 = wb[lane * 3 + 2];

    float ppi0 = ax * p01.x + ay * p23.y;
    float ppi1 = ax * p01.y + ay * p45.x;
    float ppi2 = ax * p23.x + ay * p45.y;
    float pa0  = ax * a01.x + ay * a23.y;
    float pa1  = ax * a01.y + ay * a45.x;
    float pa2  = ax * a23.x + ay * a45.y;
    float pb0  = ax * b01.x + ay * b23.y;
    float pb1  = ax * b01.y + ay * b45.x;
    float pb2  = ax * b23.x + ay * b45.y;

#pragma unroll
    for (int s = 32; s >= 1; s >>= 1) {
        ppi0 += __shfl_xor(ppi0, s, 64);
        ppi1 += __shfl_xor(ppi1, s, 64);
        ppi2 += __shfl_xor(ppi2, s, 64);
        pa0  += __shfl_xor(pa0,  s, 64);
        pa1  += __shfl_xor(pa1,  s, 64);
        pa2  += __shfl_xor(pa2,  s, 64);
        pb0  += __shfl_xor(pb0,  s, 64);
        pb1  += __shfl_xor(pb1,  s, 64);
        pb2  += __shfl_xor(pb2,  s, 64);
    }

    if (lane == 0) {
        const float z0 = ppi0 + bpi[0], z1 = ppi1 + bpi[1], z2 = ppi2 + bpi[2];
        const float mz = fmaxf(z0, fmaxf(z1, z2));
        const float e0 = expf(z0 - mz), e1 = expf(z1 - mz), e2 = expf(z2 - mz);
        const float es = e0 + e1 + e2;

        const float al0 = fminf(fmaxf(softplus_stable(pa0 + ba[0]) + 1.01f, 1.01f), 100.0f);
        const float al1 = fminf(fmaxf(softplus_stable(pa1 + ba[1]) + 1.01f, 1.01f), 100.0f);
        const float al2 = fminf(fmaxf(softplus_stable(pa2 + ba[2]) + 1.01f, 1.01f), 100.0f);
        const float bt0 = fminf(fmaxf(softplus_stable(pb0 + bb[0]) + 1.01f, 1.01f), 100.0f);
        const float bt1 = fminf(fmaxf(softplus_stable(pb1 + bb[1]) + 1.01f, 1.01f), 100.0f);
        const float bt2 = fminf(fmaxf(softplus_stable(pb2 + bb[2]) + 1.01f, 1.01f), 100.0f);

        const float pred = (e0 * (al0 / (al0 + bt0))
                          + e1 * (al1 / (al1 + bt1))
                          + e2 * (al2 / (al2 + bt2))) / es;
        out[row] = fminf(fmaxf(pred, 0.001f), 0.999f);
    }
}

extern "C" void kernel_launch(void* const* d_in, const int* in_sizes, int n_in,
                              void* d_out, int out_size, void* d_ws, size_t ws_size,
                              hipStream_t stream) {
    const float* x          = (const float*)d_in[0];
    const float* centers    = (const float*)d_in[1];
    const float* log_widths = (const float*)d_in[2];
    const float* W1   = (const float*)d_in[3];
    const float* b1   = (const float*)d_in[4];
    const float* g1   = (const float*)d_in[5];
    const float* be1  = (const float*)d_in[6];
    const float* W2   = (const float*)d_in[7];
    const float* b2   = (const float*)d_in[8];
    const float* g2   = (const float*)d_in[9];
    const float* be2  = (const float*)d_in[10];
    const float* Wr   = (const float*)d_in[11];
    const float* br   = (const float*)d_in[12];
    const float* att  = (const float*)d_in[13];
    const float* bias = (const float*)d_in[14];
    const float* Wpi  = (const float*)d_in[15];
    const float* bpi  = (const float*)d_in[16];
    const float* Wa   = (const float*)d_in[17];
    const float* ba   = (const float*)d_in[18];
    const float* Wb   = (const float*)d_in[19];
    const float* bb   = (const float*)d_in[20];

    // ---- workspace layout (byte offsets, 16B-aligned) ----
    char* ws = (char*)d_ws;
    float*          wsoft = (float*)(ws + 0);          //   256 B
    float*          rbias = (float*)(ws + 1024);       //   512 B
    float*          crw2  = (float*)(ws + 8192);       //  32 KB (float2[4096])
    float*          Pk    = (float*)(ws + 65536);      // 192 KB used (of 256 KB)
    float*          xT    = (float*)(ws + 327680);     //   4 MB
    unsigned short* W1s   = (unsigned short*)(ws + 4521984);   // 1 MB
    unsigned short* Wrs   = (unsigned short*)(ws + 5570560);   // 1 MB
    unsigned short* W2s   = (unsigned short*)(ws + 6619136);   // 2 MB
    float*          agg   = (float*)(ws + 8716288);    //   8 MB

    prep_misc<<<9, 256, 0, stream>>>(att, log_widths, centers, br, bias,
                                     b1, g1, be1, b2, g2, be2,
                                     wsoft, crw2, rbias, Pk);
    prep_swz<<<1024, 256, 0, stream>>>(W1, Wr, W2, W1s, Wrs, W2s);
    prep_xtr<<<256, 256, 0, stream>>>(x, xT);
    hipMemsetAsync(agg, 0, (size_t)BQ * HD * sizeof(float), stream);

    nam_main<<<(BQ / MT) * FG, NT, 0, stream>>>(crw2, xT, W1s, Wrs, W2s, Pk,
                                                wsoft, agg);

    nam_head<<<BQ / 4, 256, 0, stream>>>(agg, rbias, Wpi, bpi, Wa, ba, Wb, bb,
                                         (float*)d_out);
}

// Round 5
// 506.924 us; speedup vs baseline: 1.3190x; 1.0305x over previous
//
#include <hip/hip_runtime.h>
#include <math.h>

// Problem constants (fixed by the reference).
#define BQ   16384
#define FQ   64
#define NBQ  64
#define HD   128
#define FG   4       // feature groups
#define FPG  16      // features per group
#define MT   128     // batch rows per block
#define NT   512     // threads (8 waves)

typedef __attribute__((ext_vector_type(8))) short s16x8;   // 8 bf16 (4 VGPRs)
typedef __attribute__((ext_vector_type(4))) float f32x4;   // MFMA C/D

// round-to-nearest-even fp32 -> bf16 (weight prep only)
__device__ __forceinline__ unsigned short f2bf(float x) {
    unsigned int u = __float_as_uint(x);
    return (unsigned short)((u + 0x7FFFu + ((u >> 16) & 1u)) >> 16);
}

// pack 2 f32 -> 2 bf16 (RNE), lo from first arg
__device__ __forceinline__ unsigned cvtpk_bf16(float lo, float hi) {
    unsigned r;
    asm("v_cvt_pk_bf16_f32 %0, %1, %2" : "=v"(r) : "v"(lo), "v"(hi));
    return r;
}

__device__ __forceinline__ float softplus_stable(float v) {
    return (v > 0.0f) ? (v + log1pf(expf(-v))) : log1pf(expf(v));
}

// tanh-form gelu as sigmoid: gelu(v) = v / (1 + exp(-(1.5957691 v + 0.07135481 v^3)))
__device__ __forceinline__ f32x4 gelu4(f32x4 v) {
    const f32x4 v2 = v * v;
    const f32x4 tt = v2 * (-0.07135481f) + (-1.5957691f);
    const f32x4 s  = v * tt;
    f32x4 r;
    r[0] = __fdividef(v[0], 1.0f + __expf(s[0]));
    r[1] = __fdividef(v[1], 1.0f + __expf(s[1]));
    r[2] = __fdividef(v[2], 1.0f + __expf(s[2]));
    r[3] = __fdividef(v[3], 1.0f + __expf(s[3]));
    return r;
}

// async 16B global->LDS (LDS dest wave-uniform base + lane*16)
__device__ __forceinline__ void load16_lds(const unsigned short* g, unsigned short* l) {
    __builtin_amdgcn_global_load_lds(
        (const __attribute__((address_space(1))) unsigned int*)(uintptr_t)g,
        (__attribute__((address_space(3))) unsigned int*)(uintptr_t)l,
        16, 0, 0);
}

// h-dim permutation: C-tile (nt, row r=4q+i) -> h = 32*(nt>>1) + 8*q + 4*(nt&1) + i.
// Chosen so lane (q) holds exactly h in {8q..8q+7} (mod 32): GEMM2's B-fragment
// k = 32c + 8q + j is then IN-LANE -- no cross-lane transpose at all.

// ---------------- prep A: softmax + rbf coeffs + folded head bias + LN packs ----
// Pk layout (per (f, hg), hg = h>>2, 6 float4s = 96B):
//   [b1(4h), g1(4h), be1(4h), b2(4h), g2(4h), be2(4h)]
__global__ void __launch_bounds__(256) prep_misc(
    const float* __restrict__ att, const float* __restrict__ log_widths,
    const float* __restrict__ centers, const float* __restrict__ br,
    const float* __restrict__ bias,
    const float* __restrict__ b1, const float* __restrict__ g1, const float* __restrict__ be1,
    const float* __restrict__ b2, const float* __restrict__ g2, const float* __restrict__ be2,
    float* __restrict__ wsoft, float* __restrict__ crw2, float* __restrict__ rbias,
    float* __restrict__ Pk)
{
    const int t = threadIdx.x;
    if (blockIdx.x == 0) {
        __shared__ float ws[64];
        if (t < 64) {
            float v = att[t];
            float m = v;
#pragma unroll
            for (int s = 32; s >= 1; s >>= 1) m = fmaxf(m, __shfl_xor(m, s, 64));
            float e = expf(v - m);
            float ssum = e;
#pragma unroll
            for (int s = 32; s >= 1; s >>= 1) ssum += __shfl_xor(ssum, s, 64);
            const float w = e / ssum;
            ws[t] = w;
            wsoft[t] = w;
        }
        __syncthreads();
        for (int i = t; i < FQ * NBQ; i += 256) {
            float lw = fminf(fmaxf(log_widths[i], -5.0f), 5.0f);
            const float rw = 1.0f / (expf(lw) + 0.1f);
            ((float2*)crw2)[i] = make_float2(rw, -centers[i] * rw);
        }
        if (t < HD) {
            float s = bias[t];
            for (int f = 0; f < FQ; ++f) s += 0.1f * ws[f] * br[f * HD + t];
            rbias[t] = s;
        }
    } else {
        const int id = (blockIdx.x - 1) * 256 + t;   // id = f*32 + hg
        if (id < FQ * 32) {
            float4* dst = (float4*)Pk + (size_t)id * 6;
            dst[0] = ((const float4*)b1)[id];
            dst[1] = ((const float4*)g1)[id];
            dst[2] = ((const float4*)be1)[id];
            dst[3] = ((const float4*)b2)[id];
            dst[4] = ((const float4*)g2)[id];
            dst[5] = ((const float4*)be2)[id];
        }
    }
}

// ---------------- prep B: weight convert + swizzle into MFMA A-frag order ----
// A-frag for 16x16x32: lane l holds A[row = l&15][k = (l>>4)*8 + j], j=0..7.
// We store W^T as A with the sigma row-permutation on the h axis.
// W1 and Wr are packed ADJACENT per feature into W1r (32 KB / f): W1 at 0, Wr at 8192.
__global__ void __launch_bounds__(256) prep_swz(
    const float* __restrict__ W1, const float* __restrict__ Wr, const float* __restrict__ W2,
    unsigned short* __restrict__ W1r, unsigned short* __restrict__ W2s)
{
    const int gid = blockIdx.x * 256 + threadIdx.x;
    const int l = gid & 63;
    const int r = l & 15;
    const int sig_base = ((r >> 2) << 3) + (r & 3);   // 8*(r>>2) + (r&3)
    if (gid < 131072) {
        // W1 / Wr: [F][64][128], K=64 -> 2 k-tiles
        const int id = gid & 65535;
        const float* W    = (gid < 65536) ? W1 : Wr;
        const int half    = (gid < 65536) ? 0 : 8192;
        const int c  = (id >> 6) & 1;
        const int nt = (id >> 7) & 7;
        const int f  = id >> 10;
        const int hrow = ((nt >> 1) << 5) + ((nt & 1) << 2) + sig_base;
        const float* src = W + ((size_t)(f * 64 + c * 32 + (l >> 4) * 8)) * HD + hrow;
        s16x8 o;
#pragma unroll
        for (int j = 0; j < 8; ++j) o[j] = (short)f2bf(src[(size_t)j * HD]);
        *(s16x8*)(W1r + (size_t)f * 16384 + half + ((size_t)((nt * 2 + c) * 64 + l)) * 8) = o;
    } else {
        // W2: [F][128][128], K=128 -> 4 k-tiles (k = h1 in STANDARD order)
        const int id = gid - 131072;
        const int c  = (id >> 6) & 3;
        const int nt = (id >> 8) & 7;
        const int f  = id >> 11;
        const int hrow = ((nt >> 1) << 5) + ((nt & 1) << 2) + sig_base;
        const float* src = W2 + ((size_t)(f * 128 + c * 32 + (l >> 4) * 8)) * HD + hrow;
        s16x8 o;
#pragma unroll
        for (int j = 0; j < 8; ++j) o[j] = (short)f2bf(src[(size_t)j * HD]);
        *(s16x8*)(W2s + (size_t)f * 16384 + ((size_t)((nt * 4 + c) * 64 + l)) * 8) = o;
    }
}

// ---------------- prep C: LDS-tiled x transpose ----------------
__global__ void __launch_bounds__(256) prep_xtr(const float* __restrict__ x,
                                                float* __restrict__ xT) {
    __shared__ float tile[64][65];
    const int t  = threadIdx.x;
    const int b0 = blockIdx.x * 64;
    {
        const int row = t & 63, cg = (t >> 6) * 16;
        const float4* src = (const float4*)(x + (size_t)(b0 + row) * FQ + cg);
#pragma unroll
        for (int i = 0; i < 4; ++i) {
            const float4 v = src[i];
            tile[row][cg + i * 4 + 0] = v.x;
            tile[row][cg + i * 4 + 1] = v.y;
            tile[row][cg + i * 4 + 2] = v.z;
            tile[row][cg + i * 4 + 3] = v.w;
        }
    }
    __syncthreads();
    {
        const int f = t >> 2, r0 = (t & 3) * 16;
        float* dst = xT + (size_t)f * BQ + b0 + r0;
#pragma unroll
        for (int i = 0; i < 16; ++i) dst[i] = tile[r0 + i][f];
    }
}

// ---------------- fused MFMA NAM body (swapped-operand, all-register middle) ----
// grid 512 = 4 fgroups x 128 row-tiles. 512 threads = 8 waves, 16 batch cols/wave.
// Register-pressure-trimmed (round-4): no u[16] staging array, single W1r base.
__global__ void __launch_bounds__(NT, 4) nam_main(
    const float* __restrict__ crw2,
    const float* __restrict__ xT,
    const unsigned short* __restrict__ W1r,
    const unsigned short* __restrict__ W2s,
    const float* __restrict__ Pk,
    const float* __restrict__ wsoft,
    float* __restrict__ agg)
{
    __shared__ __align__(16) unsigned short smem[32768];   // 64 KB
    unsigned short* bufA = smem;            // 32 KB: W1 + Wr
    unsigned short* bufB = smem + 16384;    // 32 KB: W2

    const int t  = threadIdx.x;
    const int ln = t & 63;
    const int wv = t >> 6;
    const int n  = ln & 15;
    const int q  = ln >> 4;
    const int fb = ln * 8;               // lane frag base (shorts)
    const int fg = blockIdx.x & 3;
    const int rb = blockIdx.x >> 2;
    const int b0 = rb * MT;

    f32x4 acc[8];
#pragma unroll
    for (int nt = 0; nt < 8; ++nt) acc[nt] = f32x4{0.f, 0.f, 0.f, 0.f};

    // ---- prologue: stage f(0) weights ----
    {
        const int f0 = fg * FPG + (rb & (FPG - 1));
        const unsigned short* g1r = W1r + (size_t)f0 * 16384;
        const unsigned short* gw2 = W2s + (size_t)f0 * 16384;
#pragma unroll
        for (int i = 0; i < 4; ++i) {
            const int chunk = i * 8 + wv;
            load16_lds(g1r + chunk * 512 + fb, bufA + chunk * 512);
        }
#pragma unroll
        for (int i = 0; i < 4; ++i) {
            const int chunk = i * 8 + wv;
            load16_lds(gw2 + chunk * 512 + fb, bufB + chunk * 512);
        }
    }

    for (int ff = 0; ff < FPG; ++ff) {
        const int f  = fg * FPG + ((ff + rb) & (FPG - 1));       // decorrelated order
        const int fn = fg * FPG + ((ff + 1 + rb) & (FPG - 1));
        const float wf   = wsoft[f];
        const float wf01 = 0.1f * wf;

        // ---- rbf B-fragments directly in registers ----
        // lane supplies B[k = bucket q*8+j][col = batch n] (a0: k 0..31, a1: 32..63)
        s16x8 a0, a1;
        {
            float xv = xT[(size_t)f * BQ + b0 + wv * 16 + n];
            xv = fminf(fmaxf(xv, -10.0f), 10.0f);
            const float4* c4 = ((const float4*)crw2) + f * 32;
            unsigned p[8];
#pragma unroll
            for (int h = 0; h < 2; ++h) {
#pragma unroll
                for (int i = 0; i < 4; ++i) {
                    const float4 cc = c4[h * 16 + q * 4 + i];   // {rw,nc, rw,nc}
                    const float d0 = fmaf(xv, cc.x, cc.y);
                    const float d1 = fmaf(xv, cc.z, cc.w);
                    const float e0 = __expf(-0.5f * d0 * d0);
                    const float e1 = __expf(-0.5f * d1 * d1);
                    p[h * 4 + i] = __builtin_amdgcn_perm(__float_as_uint(e1),
                                                         __float_as_uint(e0), 0x07060302u);
                }
            }
            int4 pa = make_int4(p[0], p[1], p[2], p[3]);
            int4 pb = make_int4(p[4], p[5], p[6], p[7]);
            a0 = *(s16x8*)&pa;
            a1 = *(s16x8*)&pb;
        }

        // C: full drain (vmcnt0) -> bufA(f) + bufB(f) visible. The DMA issued last
        // iteration had GEMM2+LN2+rbf of cover.
        __syncthreads();

        // ---- GEMM1 (hc) + GEMMr folded straight into acc ----
        f32x4 hc[8];
#pragma unroll
        for (int nt = 0; nt < 8; ++nt) {
            const s16x8 w10 = *(const s16x8*)&bufA[(nt * 2 + 0) * 512 + fb];
            const s16x8 w11 = *(const s16x8*)&bufA[(nt * 2 + 1) * 512 + fb];
            f32x4 z = f32x4{0.f, 0.f, 0.f, 0.f};
            z = __builtin_amdgcn_mfma_f32_16x16x32_bf16(w10, a0, z, 0, 0, 0);
            z = __builtin_amdgcn_mfma_f32_16x16x32_bf16(w11, a1, z, 0, 0, 0);
            hc[nt] = z;
            const s16x8 wr0 = *(const s16x8*)&bufA[8192 + (nt * 2 + 0) * 512 + fb];
            const s16x8 wr1 = *(const s16x8*)&bufA[8192 + (nt * 2 + 1) * 512 + fb];
            f32x4 y = f32x4{0.f, 0.f, 0.f, 0.f};
            y = __builtin_amdgcn_mfma_f32_16x16x32_bf16(wr0, a0, y, 0, 0, 0);
            y = __builtin_amdgcn_mfma_f32_16x16x32_bf16(wr1, a1, y, 0, 0, 0);
            acc[nt] = y * wf01 + acc[nt];   // residual folded now
        }

        // ---- LN1 pass 1: bias + stats (scalar per lane; h axis is in-lane + q) ----
        const float4* pkf = (const float4*)Pk + (size_t)f * 192 + q * 12;
        f32x4 sm4 = {0.f, 0.f, 0.f, 0.f}, sq4 = {0.f, 0.f, 0.f, 0.f};
#pragma unroll
        for (int nt = 0; nt < 8; ++nt) {
            const f32x4 bg = *(const f32x4*)(pkf + (nt >> 1) * 48 + (nt & 1) * 6);
            const f32x4 v = hc[nt] + bg;
            hc[nt] = v; sm4 += v; sq4 += v * v;
        }
        float sm = (sm4[0] + sm4[1]) + (sm4[2] + sm4[3]);
        float sq = (sq4[0] + sq4[1]) + (sq4[2] + sq4[3]);
        sm += __shfl_xor(sm, 16); sm += __shfl_xor(sm, 32);
        sq += __shfl_xor(sq, 16); sq += __shfl_xor(sq, 32);
        const float mu = sm * (1.0f / 128.0f);
        const float rs = rsqrtf(sq * (1.0f / 128.0f) - mu * mu + 1e-5f);

        // E: bufA readers done (all waves past GEMM1); trivial vmcnt drain.
        __syncthreads();

        // ---- stage W1+Wr(fn) -> bufA; stays in flight across H, drained at next C ----
        if (ff < FPG - 1) {
            const unsigned short* g1r = W1r + (size_t)fn * 16384;
#pragma unroll
            for (int i = 0; i < 4; ++i) {
                const int chunk = i * 8 + wv;
                load16_lds(g1r + chunk * 512 + fb, bufA + chunk * 512);
            }
        }

        // ---- LN1 pass 2 + gelu + pack PAIRWISE into bfr (kills u[16] pressure) ----
        // bfr[c] consumes exactly hc[2c], hc[2c+1]; sigma makes it the in-lane
        // GEMM2 B-fragment for k-tile c.
        s16x8 bfr[4];
#pragma unroll
        for (int c = 0; c < 4; ++c) {
            const f32x4 gg0 = *(const f32x4*)(pkf + c * 48 + 1);
            const f32x4 bb0 = *(const f32x4*)(pkf + c * 48 + 2);
            const f32x4 gg1 = *(const f32x4*)(pkf + c * 48 + 6 + 1);
            const f32x4 bb1 = *(const f32x4*)(pkf + c * 48 + 6 + 2);
            const f32x4 z0 = gelu4((hc[2 * c]     - mu) * (gg0 * rs) + bb0);
            const f32x4 z1 = gelu4((hc[2 * c + 1] - mu) * (gg1 * rs) + bb1);
            int4 w = make_int4(cvtpk_bf16(z0[0], z0[1]), cvtpk_bf16(z0[2], z0[3]),
                               cvtpk_bf16(z1[0], z1[1]), cvtpk_bf16(z1[2], z1[3]));
            bfr[c] = *(s16x8*)&w;
        }

        // ---- GEMM2: A = W2 frags (LDS), B = bfr (registers, K=128) ----
        f32x4 h2[8];
#pragma unroll
        for (int nt = 0; nt < 8; ++nt) {
            f32x4 z = f32x4{0.f, 0.f, 0.f, 0.f};
#pragma unroll
            for (int c = 0; c < 4; ++c) {
                const s16x8 w2f = *(const s16x8*)&bufB[(nt * 4 + c) * 512 + fb];
                z = __builtin_amdgcn_mfma_f32_16x16x32_bf16(w2f, bfr[c], z, 0, 0, 0);
            }
            h2[nt] = z;
        }

        // H: raw barrier -- bufB readers done; W1r(fn) DMA deliberately crosses.
        __builtin_amdgcn_sched_barrier(0);
        __builtin_amdgcn_s_barrier();
        __builtin_amdgcn_sched_barrier(0);

        // ---- stage W2(fn) -> bufB; covered by LN2 + next rbf, drained at next C ----
        if (ff < FPG - 1) {
            const unsigned short* gw2 = W2s + (size_t)fn * 16384;
#pragma unroll
            for (int i = 0; i < 4; ++i) {
                const int chunk = i * 8 + wv;
                load16_lds(gw2 + chunk * 512 + fb, bufB + chunk * 512);
            }
        }

        // ---- LN2 (+b2), gelu, attention weight into acc ----
        f32x4 tm4 = {0.f, 0.f, 0.f, 0.f}, tq4 = {0.f, 0.f, 0.f, 0.f};
#pragma unroll
        for (int nt = 0; nt < 8; ++nt) {
            const f32x4 bg = *(const f32x4*)(pkf + (nt >> 1) * 48 + (nt & 1) * 6 + 3);
            const f32x4 v = h2[nt] + bg;
            h2[nt] = v; tm4 += v; tq4 += v * v;
        }
        float tm = (tm4[0] + tm4[1]) + (tm4[2] + tm4[3]);
        float tq = (tq4[0] + tq4[1]) + (tq4[2] + tq4[3]);
        tm += __shfl_xor(tm, 16); tm += __shfl_xor(tm, 32);
        tq += __shfl_xor(tq, 16); tq += __shfl_xor(tq, 32);
        const float mu2 = tm * (1.0f / 128.0f);
        const float rs2 = rsqrtf(tq * (1.0f / 128.0f) - mu2 * mu2 + 1e-5f);
#pragma unroll
        for (int nt = 0; nt < 8; ++nt) {
            const f32x4 gg = *(const f32x4*)(pkf + (nt >> 1) * 48 + (nt & 1) * 6 + 4);
            const f32x4 bb = *(const f32x4*)(pkf + (nt >> 1) * 48 + (nt & 1) * 6 + 5);
            const f32x4 y = (h2[nt] - mu2) * (gg * rs2) + bb;
            acc[nt] = gelu4(y) * wf + acc[nt];
        }
    }

    // ---- epilogue: LDS re-coalesce (128x128 f32 tile, XOR-swizzled) ----
    // All waves passed barrier H of the last iteration => no LDS readers remain,
    // no DMA in flight (last iter staged nothing). Safe to overwrite smem.
    {
        float* fs = (float*)smem;
        const int r = wv * 16 + n;               // this lane's local batch row
#pragma unroll
        for (int nt = 0; nt < 8; ++nt) {
            const int col  = ((nt >> 1) << 5) + (q << 3) + ((nt & 1) << 2);
            const int byte = r * 512 + col * 4;
            const int sw   = byte ^ ((r & 7) << 4);   // bank-spread, 16B-aligned
            *(f32x4*)((char*)fs + sw) = acc[nt];
        }
        __syncthreads();
        // wave wv drains rows [wv*16, wv*16+16); per instruction: 64 lanes hit
        // 64 CONSECUTIVE floats (256B) -> hardware-mergeable atomics.
        float* aggp = agg + (size_t)b0 * HD;
#pragma unroll
        for (int rr = 0; rr < 16; ++rr) {
            const int row = wv * 16 + rr;
#pragma unroll
            for (int half = 0; half < 2; ++half) {
                const int byte = row * 512 + half * 256 + ln * 4;
                const int sw   = byte ^ ((row & 7) << 4);
                const float v  = *(const float*)((const char*)fs + sw);
                atomicAdd(aggp + (size_t)row * HD + half * 64 + ln, v);
            }
        }
    }
}

// ---------------- mixture-beta head: one wave per batch row ----------------
__global__ void __launch_bounds__(256) nam_head(
    const float* __restrict__ agg, const float* __restrict__ rbias,
    const float* __restrict__ Wpi, const float* __restrict__ bpi,
    const float* __restrict__ Wa,  const float* __restrict__ ba,
    const float* __restrict__ Wb,  const float* __restrict__ bb,
    float* __restrict__ out)
{
    const int gid  = blockIdx.x * blockDim.x + threadIdx.x;
    const int row  = gid >> 6;
    const int lane = threadIdx.x & 63;
    if (row >= BQ) return;

    const float2 p  = ((const float2*)(agg + (size_t)row * HD))[lane];
    const float2 rb = ((const float2*)rbias)[lane];
    const float ax = p.x + rb.x;
    const float ay = p.y + rb.y;

    const float2* wp = (const float2*)Wpi;
    const float2* wa = (const float2*)Wa;
    const float2* wb = (const float2*)Wb;
    const float2 p01 = wp[lane * 3], p23 = wp[lane * 3 + 1], p45 = wp[lane * 3 + 2];
    const float2 a01 = wa[lane * 3], a23 = wa[lane * 3 + 1], a45 = wa[lane * 3 + 2];
    const float2 b01 = wb[lane * 3], b23 = wb[lane * 3 + 1], b45 = wb[lane * 3 + 2];

    float ppi0 = ax * p01.x + ay * p23.y;
    float ppi1 = ax * p01.y + ay * p45.x;
    float ppi2 = ax * p23.x + ay * p45.y;
    float pa0  = ax * a01.x + ay * a23.y;
    float pa1  = ax * a01.y + ay * a45.x;
    float pa2  = ax * a23.x + ay * a45.y;
    float pb0  = ax * b01.x + ay * b23.y;
    float pb1  = ax * b01.y + ay * b45.x;
    float pb2  = ax * b23.x + ay * b45.y;

#pragma unroll
    for (int s = 32; s >= 1; s >>= 1) {
        ppi0 += __shfl_xor(ppi0, s, 64);
        ppi1 += __shfl_xor(ppi1, s, 64);
        ppi2 += __shfl_xor(ppi2, s, 64);
        pa0  += __shfl_xor(pa0,  s, 64);
        pa1  += __shfl_xor(pa1,  s, 64);
        pa2  += __shfl_xor(pa2,  s, 64);
        pb0  += __shfl_xor(pb0,  s, 64);
        pb1  += __shfl_xor(pb1,  s, 64);
        pb2  += __shfl_xor(pb2,  s, 64);
    }

    if (lane == 0) {
        const float z0 = ppi0 + bpi[0], z1 = ppi1 + bpi[1], z2 = ppi2 + bpi[2];
        const float mz = fmaxf(z0, fmaxf(z1, z2));
        const float e0 = expf(z0 - mz), e1 = expf(z1 - mz), e2 = expf(z2 - mz);
        const float es = e0 + e1 + e2;

        const float al0 = fminf(fmaxf(softplus_stable(pa0 + ba[0]) + 1.01f, 1.01f), 100.0f);
        const float al1 = fminf(fmaxf(softplus_stable(pa1 + ba[1]) + 1.01f, 1.01f), 100.0f);
        const float al2 = fminf(fmaxf(softplus_stable(pa2 + ba[2]) + 1.01f, 1.01f), 100.0f);
        const float bt0 = fminf(fmaxf(softplus_stable(pb0 + bb[0]) + 1.01f, 1.01f), 100.0f);
        const float bt1 = fminf(fmaxf(softplus_stable(pb1 + bb[1]) + 1.01f, 1.01f), 100.0f);
        const float bt2 = fminf(fmaxf(softplus_stable(pb2 + bb[2]) + 1.01f, 1.01f), 100.0f);

        const float pred = (e0 * (al0 / (al0 + bt0))
                          + e1 * (al1 / (al1 + bt1))
                          + e2 * (al2 / (al2 + bt2))) / es;
        out[row] = fminf(fmaxf(pred, 0.001f), 0.999f);
    }
}

extern "C" void kernel_launch(void* const* d_in, const int* in_sizes, int n_in,
                              void* d_out, int out_size, void* d_ws, size_t ws_size,
                              hipStream_t stream) {
    const float* x          = (const float*)d_in[0];
    const float* centers    = (const float*)d_in[1];
    const float* log_widths = (const float*)d_in[2];
    const float* W1   = (const float*)d_in[3];
    const float* b1   = (const float*)d_in[4];
    const float* g1   = (const float*)d_in[5];
    const float* be1  = (const float*)d_in[6];
    const float* W2   = (const float*)d_in[7];
    const float* b2   = (const float*)d_in[8];
    const float* g2   = (const float*)d_in[9];
    const float* be2  = (const float*)d_in[10];
    const float* Wr   = (const float*)d_in[11];
    const float* br   = (const float*)d_in[12];
    const float* att  = (const float*)d_in[13];
    const float* bias = (const float*)d_in[14];
    const float* Wpi  = (const float*)d_in[15];
    const float* bpi  = (const float*)d_in[16];
    const float* Wa   = (const float*)d_in[17];
    const float* ba   = (const float*)d_in[18];
    const float* Wb   = (const float*)d_in[19];
    const float* bb   = (const float*)d_in[20];

    // ---- workspace layout (byte offsets, 16B-aligned) ----
    char* ws = (char*)d_ws;
    float*          wsoft = (float*)(ws + 0);          //   256 B
    float*          rbias = (float*)(ws + 1024);       //   512 B
    float*          crw2  = (float*)(ws + 8192);       //  32 KB (float2[4096])
    float*          Pk    = (float*)(ws + 65536);      // 192 KB used (of 256 KB)
    float*          xT    = (float*)(ws + 327680);     //   4 MB
    unsigned short* W1r   = (unsigned short*)(ws + 4521984);   // 2 MB (W1+Wr interleaved per f)
    unsigned short* W2s   = (unsigned short*)(ws + 6619136);   // 2 MB
    float*          agg   = (float*)(ws + 8716288);    //   8 MB

    prep_misc<<<9, 256, 0, stream>>>(att, log_widths, centers, br, bias,
                                     b1, g1, be1, b2, g2, be2,
                                     wsoft, crw2, rbias, Pk);
    prep_swz<<<1024, 256, 0, stream>>>(W1, Wr, W2, W1r, W2s);
    prep_xtr<<<256, 256, 0, stream>>>(x, xT);
    hipMemsetAsync(agg, 0, (size_t)BQ * HD * sizeof(float), stream);

    nam_main<<<(BQ / MT) * FG, NT, 0, stream>>>(crw2, xT, W1r, W2s, Pk,
                                                wsoft, agg);

    nam_head<<<BQ / 4, 256, 0, stream>>>(agg, rbias, Wpi, bpi, Wa, ba, Wb, bb,
                                         (float*)d_out);
}

// Round 6
// 390.091 us; speedup vs baseline: 1.7141x; 1.2995x over previous
//
#include <hip/hip_runtime.h>
#include <math.h>

// Problem constants (fixed by the reference).
#define BQ   16384
#define FQ   64
#define NBQ  64
#define HD   128
#define FG   4       // feature groups
#define FPG  16      // features per group
#define MT   128     // batch rows per block
#define NT   512     // threads (8 waves)

typedef __attribute__((ext_vector_type(8))) short s16x8;   // 8 bf16 (4 VGPRs)
typedef __attribute__((ext_vector_type(4))) float f32x4;   // MFMA C/D

// round-to-nearest-even fp32 -> bf16 (weight prep only)
__device__ __forceinline__ unsigned short f2bf(float x) {
    unsigned int u = __float_as_uint(x);
    return (unsigned short)((u + 0x7FFFu + ((u >> 16) & 1u)) >> 16);
}

// pack 2 f32 -> 2 bf16 (RNE), lo from first arg
__device__ __forceinline__ unsigned cvtpk_bf16(float lo, float hi) {
    unsigned r;
    asm("v_cvt_pk_bf16_f32 %0, %1, %2" : "=v"(r) : "v"(lo), "v"(hi));
    return r;
}

__device__ __forceinline__ float softplus_stable(float v) {
    return (v > 0.0f) ? (v + log1pf(expf(-v))) : log1pf(expf(v));
}

// tanh-form gelu as sigmoid: gelu(v) = v / (1 + exp(-(1.5957691 v + 0.07135481 v^3)))
__device__ __forceinline__ f32x4 gelu4(f32x4 v) {
    const f32x4 v2 = v * v;
    const f32x4 tt = v2 * (-0.07135481f) + (-1.5957691f);
    const f32x4 s  = v * tt;
    f32x4 r;
    r[0] = __fdividef(v[0], 1.0f + __expf(s[0]));
    r[1] = __fdividef(v[1], 1.0f + __expf(s[1]));
    r[2] = __fdividef(v[2], 1.0f + __expf(s[2]));
    r[3] = __fdividef(v[3], 1.0f + __expf(s[3]));
    return r;
}

// async 16B global->LDS (LDS dest wave-uniform base + lane*16)
__device__ __forceinline__ void load16_lds(const unsigned short* g, unsigned short* l) {
    __builtin_amdgcn_global_load_lds(
        (const __attribute__((address_space(1))) unsigned int*)(uintptr_t)g,
        (__attribute__((address_space(3))) unsigned int*)(uintptr_t)l,
        16, 0, 0);
}

// h-dim permutation: C-tile (nt, row r=4q+i) -> h = 32*(nt>>1) + 8*q + 4*(nt&1) + i.
// Chosen so lane (q) holds exactly h in {8q..8q+7} (mod 32): GEMM2's B-fragment
// k = 32c + 8q + j is then IN-LANE -- no cross-lane transpose at all.

// ---------------- prep A: softmax + rbf coeffs + folded head bias + LN packs ----
// Pk layout (per (f, hg), hg = h>>2, 6 float4s = 96B):
//   [b1(4h), g1(4h), be1(4h), b2(4h), g2(4h), be2(4h)]
__global__ void __launch_bounds__(256) prep_misc(
    const float* __restrict__ att, const float* __restrict__ log_widths,
    const float* __restrict__ centers, const float* __restrict__ br,
    const float* __restrict__ bias,
    const float* __restrict__ b1, const float* __restrict__ g1, const float* __restrict__ be1,
    const float* __restrict__ b2, const float* __restrict__ g2, const float* __restrict__ be2,
    float* __restrict__ wsoft, float* __restrict__ crw2, float* __restrict__ rbias,
    float* __restrict__ Pk)
{
    const int t = threadIdx.x;
    if (blockIdx.x == 0) {
        __shared__ float ws[64];
        if (t < 64) {
            float v = att[t];
            float m = v;
#pragma unroll
            for (int s = 32; s >= 1; s >>= 1) m = fmaxf(m, __shfl_xor(m, s, 64));
            float e = expf(v - m);
            float ssum = e;
#pragma unroll
            for (int s = 32; s >= 1; s >>= 1) ssum += __shfl_xor(ssum, s, 64);
            const float w = e / ssum;
            ws[t] = w;
            wsoft[t] = w;
        }
        __syncthreads();
        for (int i = t; i < FQ * NBQ; i += 256) {
            float lw = fminf(fmaxf(log_widths[i], -5.0f), 5.0f);
            const float rw = 1.0f / (expf(lw) + 0.1f);
            ((float2*)crw2)[i] = make_float2(rw, -centers[i] * rw);
        }
        if (t < HD) {
            float s = bias[t];
            for (int f = 0; f < FQ; ++f) s += 0.1f * ws[f] * br[f * HD + t];
            rbias[t] = s;
        }
    } else {
        const int id = (blockIdx.x - 1) * 256 + t;   // id = f*32 + hg
        if (id < FQ * 32) {
            float4* dst = (float4*)Pk + (size_t)id * 6;
            dst[0] = ((const float4*)b1)[id];
            dst[1] = ((const float4*)g1)[id];
            dst[2] = ((const float4*)be1)[id];
            dst[3] = ((const float4*)b2)[id];
            dst[4] = ((const float4*)g2)[id];
            dst[5] = ((const float4*)be2)[id];
        }
    }
}

// ---------------- prep B: weight convert + swizzle into MFMA A-frag order ----
// A-frag for 16x16x32: lane l holds A[row = l&15][k = (l>>4)*8 + j], j=0..7.
// We store W^T as A with the sigma row-permutation on the h axis.
// W1 and Wr are packed ADJACENT per feature into W1r (32 KB / f): W1 at 0, Wr at 8192.
__global__ void __launch_bounds__(256) prep_swz(
    const float* __restrict__ W1, const float* __restrict__ Wr, const float* __restrict__ W2,
    unsigned short* __restrict__ W1r, unsigned short* __restrict__ W2s)
{
    const int gid = blockIdx.x * 256 + threadIdx.x;
    const int l = gid & 63;
    const int r = l & 15;
    const int sig_base = ((r >> 2) << 3) + (r & 3);   // 8*(r>>2) + (r&3)
    if (gid < 131072) {
        // W1 / Wr: [F][64][128], K=64 -> 2 k-tiles
        const int id = gid & 65535;
        const float* W    = (gid < 65536) ? W1 : Wr;
        const int half    = (gid < 65536) ? 0 : 8192;
        const int c  = (id >> 6) & 1;
        const int nt = (id >> 7) & 7;
        const int f  = id >> 10;
        const int hrow = ((nt >> 1) << 5) + ((nt & 1) << 2) + sig_base;
        const float* src = W + ((size_t)(f * 64 + c * 32 + (l >> 4) * 8)) * HD + hrow;
        s16x8 o;
#pragma unroll
        for (int j = 0; j < 8; ++j) o[j] = (short)f2bf(src[(size_t)j * HD]);
        *(s16x8*)(W1r + (size_t)f * 16384 + half + ((size_t)((nt * 2 + c) * 64 + l)) * 8) = o;
    } else {
        // W2: [F][128][128], K=128 -> 4 k-tiles (k = h1 in STANDARD order)
        const int id = gid - 131072;
        const int c  = (id >> 6) & 3;
        const int nt = (id >> 8) & 7;
        const int f  = id >> 11;
        const int hrow = ((nt >> 1) << 5) + ((nt & 1) << 2) + sig_base;
        const float* src = W2 + ((size_t)(f * 128 + c * 32 + (l >> 4) * 8)) * HD + hrow;
        s16x8 o;
#pragma unroll
        for (int j = 0; j < 8; ++j) o[j] = (short)f2bf(src[(size_t)j * HD]);
        *(s16x8*)(W2s + (size_t)f * 16384 + ((size_t)((nt * 4 + c) * 64 + l)) * 8) = o;
    }
}

// ---------------- prep C: LDS-tiled x transpose ----------------
__global__ void __launch_bounds__(256) prep_xtr(const float* __restrict__ x,
                                                float* __restrict__ xT) {
    __shared__ float tile[64][65];
    const int t  = threadIdx.x;
    const int b0 = blockIdx.x * 64;
    {
        const int row = t & 63, cg = (t >> 6) * 16;
        const float4* src = (const float4*)(x + (size_t)(b0 + row) * FQ + cg);
#pragma unroll
        for (int i = 0; i < 4; ++i) {
            const float4 v = src[i];
            tile[row][cg + i * 4 + 0] = v.x;
            tile[row][cg + i * 4 + 1] = v.y;
            tile[row][cg + i * 4 + 2] = v.z;
            tile[row][cg + i * 4 + 3] = v.w;
        }
    }
    __syncthreads();
    {
        const int f = t >> 2, r0 = (t & 3) * 16;
        float* dst = xT + (size_t)f * BQ + b0 + r0;
#pragma unroll
        for (int i = 0; i < 16; ++i) dst[i] = tile[r0 + i][f];
    }
}

// ---------------- fused MFMA NAM body (swapped-operand, all-register middle) ----
// grid 512 = 4 fgroups x 128 row-tiles. 512 threads = 8 waves, 16 batch cols/wave.
// Round-6: Pk[f] (3KB) and crw2[f] (512B) are LDS-staged via global_load_lds,
// double-buffered on ff-parity -- removes hoisted global float4 loads (the
// register-spill source per r3/r5 counters). rbf math moved after barrier C.
__global__ void __launch_bounds__(NT, 4) nam_main(
    const float* __restrict__ crw2,
    const float* __restrict__ xT,
    const unsigned short* __restrict__ W1r,
    const unsigned short* __restrict__ W2s,
    const float* __restrict__ Pk,
    const float* __restrict__ wsoft,
    float* __restrict__ agg)
{
    __shared__ __align__(16) unsigned short smem[32768];   // 64 KB: weights / epi tile
    __shared__ __align__(16) float pkbuf[2][768];          // 2 x 3 KB LN packs
    __shared__ __align__(16) float cwbuf[2][128];          // 2 x 512 B rbf coeffs
    unsigned short* bufA = smem;            // 32 KB: W1 + Wr
    unsigned short* bufB = smem + 16384;    // 32 KB: W2

    const int t  = threadIdx.x;
    const int ln = t & 63;
    const int wv = t >> 6;
    const int n  = ln & 15;
    const int q  = ln >> 4;
    const int fb = ln * 8;               // lane frag base (shorts)
    const int fg = blockIdx.x & 3;
    const int rb = blockIdx.x >> 2;
    const int b0 = rb * MT;

    f32x4 acc[8];
#pragma unroll
    for (int nt = 0; nt < 8; ++nt) acc[nt] = f32x4{0.f, 0.f, 0.f, 0.f};

    // ---- prologue: stage f(0) weights + params ----
    {
        const int f0 = fg * FPG + (rb & (FPG - 1));
        const unsigned short* g1r = W1r + (size_t)f0 * 16384;
        const unsigned short* gw2 = W2s + (size_t)f0 * 16384;
#pragma unroll
        for (int i = 0; i < 4; ++i) {
            const int chunk = i * 8 + wv;
            load16_lds(g1r + chunk * 512 + fb, bufA + chunk * 512);
        }
#pragma unroll
        for (int i = 0; i < 4; ++i) {
            const int chunk = i * 8 + wv;
            load16_lds(gw2 + chunk * 512 + fb, bufB + chunk * 512);
        }
        if (wv < 3)
            load16_lds((const unsigned short*)(Pk + (size_t)f0 * 768) + wv * 512 + ln * 8,
                       (unsigned short*)pkbuf[0] + wv * 512);
        if (wv == 3 && q < 2)
            load16_lds((const unsigned short*)(crw2 + (size_t)f0 * 128) + ln * 8,
                       (unsigned short*)cwbuf[0] + ln * 8);
    }

    for (int ff = 0; ff < FPG; ++ff) {
        const int f  = fg * FPG + ((ff + rb) & (FPG - 1));       // decorrelated order
        const int fn = fg * FPG + ((ff + 1 + rb) & (FPG - 1));
        const int p  = ff & 1;
        const float wf   = wsoft[f];
        const float wf01 = 0.1f * wf;

        // x value for this lane's batch col (global scalar; safe before C)
        float xv = xT[(size_t)f * BQ + b0 + wv * 16 + n];
        xv = fminf(fmaxf(xv, -10.0f), 10.0f);

        // C: full drain (vmcnt0) -> bufA/bufB/pkbuf[p]/cwbuf[p] visible.
        __syncthreads();

        // ---- rbf B-fragments from LDS-staged coeffs (post-C: staged data valid) ----
        // lane supplies B[k = bucket q*8+j][col = batch n] (a0: k 0..31, a1: 32..63)
        s16x8 a0, a1;
        {
            const float4* c4 = (const float4*)cwbuf[p];
            unsigned pk[8];
#pragma unroll
            for (int h = 0; h < 2; ++h) {
#pragma unroll
                for (int i = 0; i < 4; ++i) {
                    const float4 cc = c4[h * 16 + q * 4 + i];   // {rw,nc, rw,nc}
                    const float d0 = fmaf(xv, cc.x, cc.y);
                    const float d1 = fmaf(xv, cc.z, cc.w);
                    const float e0 = __expf(-0.5f * d0 * d0);
                    const float e1 = __expf(-0.5f * d1 * d1);
                    pk[h * 4 + i] = __builtin_amdgcn_perm(__float_as_uint(e1),
                                                          __float_as_uint(e0), 0x07060302u);
                }
            }
            int4 pa = make_int4(pk[0], pk[1], pk[2], pk[3]);
            int4 pb = make_int4(pk[4], pk[5], pk[6], pk[7]);
            a0 = *(s16x8*)&pa;
            a1 = *(s16x8*)&pb;
        }

        // ---- GEMM1 (hc) + GEMMr folded straight into acc ----
        f32x4 hc[8];
#pragma unroll
        for (int nt = 0; nt < 8; ++nt) {
            const s16x8 w10 = *(const s16x8*)&bufA[(nt * 2 + 0) * 512 + fb];
            const s16x8 w11 = *(const s16x8*)&bufA[(nt * 2 + 1) * 512 + fb];
            f32x4 z = f32x4{0.f, 0.f, 0.f, 0.f};
            z = __builtin_amdgcn_mfma_f32_16x16x32_bf16(w10, a0, z, 0, 0, 0);
            z = __builtin_amdgcn_mfma_f32_16x16x32_bf16(w11, a1, z, 0, 0, 0);
            hc[nt] = z;
            const s16x8 wr0 = *(const s16x8*)&bufA[8192 + (nt * 2 + 0) * 512 + fb];
            const s16x8 wr1 = *(const s16x8*)&bufA[8192 + (nt * 2 + 1) * 512 + fb];
            f32x4 y = f32x4{0.f, 0.f, 0.f, 0.f};
            y = __builtin_amdgcn_mfma_f32_16x16x32_bf16(wr0, a0, y, 0, 0, 0);
            y = __builtin_amdgcn_mfma_f32_16x16x32_bf16(wr1, a1, y, 0, 0, 0);
            acc[nt] = y * wf01 + acc[nt];   // residual folded now
        }

        // ---- LN1 pass 1: bias + stats (params from LDS; broadcast reads) ----
        const f32x4* pkf = (const f32x4*)pkbuf[p] + q * 12;
        f32x4 sm4 = {0.f, 0.f, 0.f, 0.f}, sq4 = {0.f, 0.f, 0.f, 0.f};
#pragma unroll
        for (int nt = 0; nt < 8; ++nt) {
            const f32x4 bg = pkf[(nt >> 1) * 48 + (nt & 1) * 6];
            const f32x4 v = hc[nt] + bg;
            hc[nt] = v; sm4 += v; sq4 += v * v;
        }
        float sm = (sm4[0] + sm4[1]) + (sm4[2] + sm4[3]);
        float sq = (sq4[0] + sq4[1]) + (sq4[2] + sq4[3]);
        sm += __shfl_xor(sm, 16); sm += __shfl_xor(sm, 32);
        sq += __shfl_xor(sq, 16); sq += __shfl_xor(sq, 32);
        const float mu = sm * (1.0f / 128.0f);
        const float rs = rsqrtf(sq * (1.0f / 128.0f) - mu * mu + 1e-5f);

        // E: bufA readers done (all waves past GEMM1); pkbuf[p] still live (dbuf).
        __syncthreads();

        // ---- stage W1+Wr(fn)+Pk(fn)+crw(fn); in flight until next C ----
        if (ff < FPG - 1) {
            const unsigned short* g1r = W1r + (size_t)fn * 16384;
#pragma unroll
            for (int i = 0; i < 4; ++i) {
                const int chunk = i * 8 + wv;
                load16_lds(g1r + chunk * 512 + fb, bufA + chunk * 512);
            }
            if (wv < 3)
                load16_lds((const unsigned short*)(Pk + (size_t)fn * 768) + wv * 512 + ln * 8,
                           (unsigned short*)pkbuf[p ^ 1] + wv * 512);
            if (wv == 3 && q < 2)
                load16_lds((const unsigned short*)(crw2 + (size_t)fn * 128) + ln * 8,
                           (unsigned short*)cwbuf[p ^ 1] + ln * 8);
        }

        // ---- LN1 pass 2 + gelu + pack PAIRWISE into bfr ----
        s16x8 bfr[4];
#pragma unroll
        for (int c = 0; c < 4; ++c) {
            const f32x4 gg0 = pkf[c * 48 + 1];
            const f32x4 bb0 = pkf[c * 48 + 2];
            const f32x4 gg1 = pkf[c * 48 + 6 + 1];
            const f32x4 bb1 = pkf[c * 48 + 6 + 2];
            const f32x4 z0 = gelu4((hc[2 * c]     - mu) * (gg0 * rs) + bb0);
            const f32x4 z1 = gelu4((hc[2 * c + 1] - mu) * (gg1 * rs) + bb1);
            int4 w = make_int4(cvtpk_bf16(z0[0], z0[1]), cvtpk_bf16(z0[2], z0[3]),
                               cvtpk_bf16(z1[0], z1[1]), cvtpk_bf16(z1[2], z1[3]));
            bfr[c] = *(s16x8*)&w;
        }

        // ---- GEMM2: A = W2 frags (LDS), B = bfr (registers, K=128) ----
        f32x4 h2[8];
#pragma unroll
        for (int nt = 0; nt < 8; ++nt) {
            f32x4 z = f32x4{0.f, 0.f, 0.f, 0.f};
#pragma unroll
            for (int c = 0; c < 4; ++c) {
                const s16x8 w2f = *(const s16x8*)&bufB[(nt * 4 + c) * 512 + fb];
                z = __builtin_amdgcn_mfma_f32_16x16x32_bf16(w2f, bfr[c], z, 0, 0, 0);
            }
            h2[nt] = z;
        }

        // H: raw barrier -- bufB readers done; W1r/Pk/cw(fn) DMA deliberately crosses.
        __builtin_amdgcn_sched_barrier(0);
        __builtin_amdgcn_s_barrier();
        __builtin_amdgcn_sched_barrier(0);

        // ---- stage W2(fn) -> bufB; covered by LN2 + next rbf, drained at next C ----
        if (ff < FPG - 1) {
            const unsigned short* gw2 = W2s + (size_t)fn * 16384;
#pragma unroll
            for (int i = 0; i < 4; ++i) {
                const int chunk = i * 8 + wv;
                load16_lds(gw2 + chunk * 512 + fb, bufB + chunk * 512);
            }
        }

        // ---- LN2 (+b2), gelu, attention weight into acc ----
        f32x4 tm4 = {0.f, 0.f, 0.f, 0.f}, tq4 = {0.f, 0.f, 0.f, 0.f};
#pragma unroll
        for (int nt = 0; nt < 8; ++nt) {
            const f32x4 bg = pkf[(nt >> 1) * 48 + (nt & 1) * 6 + 3];
            const f32x4 v = h2[nt] + bg;
            h2[nt] = v; tm4 += v; tq4 += v * v;
        }
        float tm = (tm4[0] + tm4[1]) + (tm4[2] + tm4[3]);
        float tq = (tq4[0] + tq4[1]) + (tq4[2] + tq4[3]);
        tm += __shfl_xor(tm, 16); tm += __shfl_xor(tm, 32);
        tq += __shfl_xor(tq, 16); tq += __shfl_xor(tq, 32);
        const float mu2 = tm * (1.0f / 128.0f);
        const float rs2 = rsqrtf(tq * (1.0f / 128.0f) - mu2 * mu2 + 1e-5f);
#pragma unroll
        for (int nt = 0; nt < 8; ++nt) {
            const f32x4 gg = pkf[(nt >> 1) * 48 + (nt & 1) * 6 + 4];
            const f32x4 bb = pkf[(nt >> 1) * 48 + (nt & 1) * 6 + 5];
            const f32x4 y = (h2[nt] - mu2) * (gg * rs2) + bb;
            acc[nt] = gelu4(y) * wf + acc[nt];
        }
    }

    // ---- epilogue: LDS re-coalesce (128x128 f32 tile, XOR-swizzled) ----
    // All waves passed barrier H of the last iteration => no LDS readers remain,
    // no DMA in flight (last iter staged nothing). Safe to overwrite smem.
    {
        float* fs = (float*)smem;
        const int r = wv * 16 + n;               // this lane's local batch row
#pragma unroll
        for (int nt = 0; nt < 8; ++nt) {
            const int col  = ((nt >> 1) << 5) + (q << 3) + ((nt & 1) << 2);
            const int byte = r * 512 + col * 4;
            const int sw   = byte ^ ((r & 7) << 4);   // bank-spread, 16B-aligned
            *(f32x4*)((char*)fs + sw) = acc[nt];
        }
        __syncthreads();
        // wave wv drains rows [wv*16, wv*16+16); per instruction: 64 lanes hit
        // 64 CONSECUTIVE floats (256B) -> hardware-mergeable atomics.
        float* aggp = agg + (size_t)b0 * HD;
#pragma unroll
        for (int rr = 0; rr < 16; ++rr) {
            const int row = wv * 16 + rr;
#pragma unroll
            for (int half = 0; half < 2; ++half) {
                const int byte = row * 512 + half * 256 + ln * 4;
                const int sw   = byte ^ ((row & 7) << 4);
                const float v  = *(const float*)((const char*)fs + sw);
                atomicAdd(aggp + (size_t)row * HD + half * 64 + ln, v);
            }
        }
    }
}

// ---------------- mixture-beta head: one wave per batch row ----------------
__global__ void __launch_bounds__(256) nam_head(
    const float* __restrict__ agg, const float* __restrict__ rbias,
    const float* __restrict__ Wpi, const float* __restrict__ bpi,
    const float* __restrict__ Wa,  const float* __restrict__ ba,
    const float* __restrict__ Wb,  const float* __restrict__ bb,
    float* __restrict__ out)
{
    const int gid  = blockIdx.x * blockDim.x + threadIdx.x;
    const int row  = gid >> 6;
    const int lane = threadIdx.x & 63;
    if (row >= BQ) return;

    const float2 p  = ((const float2*)(agg + (size_t)row * HD))[lane];
    const float2 rb = ((const float2*)rbias)[lane];
    const float ax = p.x + rb.x;
    const float ay = p.y + rb.y;

    const float2* wp = (const float2*)Wpi;
    const float2* wa = (const float2*)Wa;
    const float2* wb = (const float2*)Wb;
    const float2 p01 = wp[lane * 3], p23 = wp[lane * 3 + 1], p45 = wp[lane * 3 + 2];
    const float2 a01 = wa[lane * 3], a23 = wa[lane * 3 + 1], a45 = wa[lane * 3 + 2];
    const float2 b01 = wb[lane * 3], b23 = wb[lane * 3 + 1], b45 = wb[lane * 3 + 2];

    float ppi0 = ax * p01.x + ay * p23.y;
    float ppi1 = ax * p01.y + ay * p45.x;
    float ppi2 = ax * p23.x + ay * p45.y;
    float pa0  = ax * a01.x + ay * a23.y;
    float pa1  = ax * a01.y + ay * a45.x;
    float pa2  = ax * a23.x + ay * a45.y;
    float pb0  = ax * b01.x + ay * b23.y;
    float pb1  = ax * b01.y + ay * b45.x;
    float pb2  = ax * b23.x + ay * b45.y;

#pragma unroll
    for (int s = 32; s >= 1; s >>= 1) {
        ppi0 += __shfl_xor(ppi0, s, 64);
        ppi1 += __shfl_xor(ppi1, s, 64);
        ppi2 += __shfl_xor(ppi2, s, 64);
        pa0  += __shfl_xor(pa0,  s, 64);
        pa1  += __shfl_xor(pa1,  s, 64);
        pa2  += __shfl_xor(pa2,  s, 64);
        pb0  += __shfl_xor(pb0,  s, 64);
        pb1  += __shfl_xor(pb1,  s, 64);
        pb2  += __shfl_xor(pb2,  s, 64);
    }

    if (lane == 0) {
        const float z0 = ppi0 + bpi[0], z1 = ppi1 + bpi[1], z2 = ppi2 + bpi[2];
        const float mz = fmaxf(z0, fmaxf(z1, z2));
        const float e0 = expf(z0 - mz), e1 = expf(z1 - mz), e2 = expf(z2 - mz);
        const float es = e0 + e1 + e2;

        const float al0 = fminf(fmaxf(softplus_stable(pa0 + ba[0]) + 1.01f, 1.01f), 100.0f);
        const float al1 = fminf(fmaxf(softplus_stable(pa1 + ba[1]) + 1.01f, 1.01f), 100.0f);
        const float al2 = fminf(fmaxf(softplus_stable(pa2 + ba[2]) + 1.01f, 1.01f), 100.0f);
        const float bt0 = fminf(fmaxf(softplus_stable(pb0 + bb[0]) + 1.01f, 1.01f), 100.0f);
        const float bt1 = fminf(fmaxf(softplus_stable(pb1 + bb[1]) + 1.01f, 1.01f), 100.0f);
        const float bt2 = fminf(fmaxf(softplus_stable(pb2 + bb[2]) + 1.01f, 1.01f), 100.0f);

        const float pred = (e0 * (al0 / (al0 + bt0))
                          + e1 * (al1 / (al1 + bt1))
                          + e2 * (al2 / (al2 + bt2))) / es;
        out[row] = fminf(fmaxf(pred, 0.001f), 0.999f);
    }
}

extern "C" void kernel_launch(void* const* d_in, const int* in_sizes, int n_in,
                              void* d_out, int out_size, void* d_ws, size_t ws_size,
                              hipStream_t stream) {
    const float* x          = (const float*)d_in[0];
    const float* centers    = (const float*)d_in[1];
    const float* log_widths = (const float*)d_in[2];
    const float* W1   = (const float*)d_in[3];
    const float* b1   = (const float*)d_in[4];
    const float* g1   = (const float*)d_in[5];
    const float* be1  = (const float*)d_in[6];
    const float* W2   = (const float*)d_in[7];
    const float* b2   = (const float*)d_in[8];
    const float* g2   = (const float*)d_in[9];
    const float* be2  = (const float*)d_in[10];
    const float* Wr   = (const float*)d_in[11];
    const float* br   = (const float*)d_in[12];
    const float* att  = (const float*)d_in[13];
    const float* bias = (const float*)d_in[14];
    const float* Wpi  = (const float*)d_in[15];
    const float* bpi  = (const float*)d_in[16];
    const float* Wa   = (const float*)d_in[17];
    const float* ba   = (const float*)d_in[18];
    const float* Wb   = (const float*)d_in[19];
    const float* bb   = (const float*)d_in[20];

    // ---- workspace layout (byte offsets, 16B-aligned) ----
    char* ws = (char*)d_ws;
    float*          wsoft = (float*)(ws + 0);          //   256 B
    float*          rbias = (float*)(ws + 1024);       //   512 B
    float*          crw2  = (float*)(ws + 8192);       //  32 KB (float2[4096])
    float*          Pk    = (float*)(ws + 65536);      // 192 KB used (of 256 KB)
    float*          xT    = (float*)(ws + 327680);     //   4 MB
    unsigned short* W1r   = (unsigned short*)(ws + 4521984);   // 2 MB (W1+Wr per f)
    unsigned short* W2s   = (unsigned short*)(ws + 6619136);   // 2 MB
    float*          agg   = (float*)(ws + 8716288);    //   8 MB

    prep_misc<<<9, 256, 0, stream>>>(att, log_widths, centers, br, bias,
                                     b1, g1, be1, b2, g2, be2,
                                     wsoft, crw2, rbias, Pk);
    prep_swz<<<1024, 256, 0, stream>>>(W1, Wr, W2, W1r, W2s);
    prep_xtr<<<256, 256, 0, stream>>>(x, xT);
    hipMemsetAsync(agg, 0, (size_t)BQ * HD * sizeof(float), stream);

    nam_main<<<(BQ / MT) * FG, NT, 0, stream>>>(crw2, xT, W1r, W2s, Pk,
                                                wsoft, agg);

    nam_head<<<BQ / 4, 256, 0, stream>>>(agg, rbias, Wpi, bpi, Wa, ba, Wb, bb,
                                         (float*)d_out);
}

// Round 8
// 373.495 us; speedup vs baseline: 1.7902x; 1.0444x over previous
//
#include <hip/hip_runtime.h>
#include <math.h>

// Problem constants (fixed by the reference).
#define BQ   16384
#define FQ   64
#define NBQ  64
#define HD   128
#define FG   4       // feature groups
#define FPG  16      // features per group
#define MT   128     // batch rows per block
#define NT   512     // threads (8 waves)

typedef __attribute__((ext_vector_type(8))) short s16x8;   // 8 bf16 (4 VGPRs)
typedef __attribute__((ext_vector_type(4))) float f32x4;   // MFMA C/D

// round-to-nearest-even fp32 -> bf16 (weight prep only)
__device__ __forceinline__ unsigned short f2bf(float x) {
    unsigned int u = __float_as_uint(x);
    return (unsigned short)((u + 0x7FFFu + ((u >> 16) & 1u)) >> 16);
}

// pack 2 f32 -> 2 bf16 (RNE), lo from first arg
__device__ __forceinline__ unsigned cvtpk_bf16(float lo, float hi) {
    unsigned r;
    asm("v_cvt_pk_bf16_f32 %0, %1, %2" : "=v"(r) : "v"(lo), "v"(hi));
    return r;
}

__device__ __forceinline__ float softplus_stable(float v) {
    return (v > 0.0f) ? (v + log1pf(expf(-v))) : log1pf(expf(v));
}

// tanh-form gelu as sigmoid with log2e FOLDED into the cubic constants:
// gelu(v) = v / (1 + exp2(v*(c3*v^2 + c1))), c3 = -0.07135481*log2e, c1 = -1.5957691*log2e
__device__ __forceinline__ f32x4 gelu4(f32x4 v) {
    const f32x4 v2 = v * v;
    const f32x4 tt = v2 * (-0.10294343f) + (-2.3022152f);
    const f32x4 s  = v * tt;
    f32x4 r;
    r[0] = __fdividef(v[0], 1.0f + __builtin_amdgcn_exp2f(s[0]));
    r[1] = __fdividef(v[1], 1.0f + __builtin_amdgcn_exp2f(s[1]));
    r[2] = __fdividef(v[2], 1.0f + __builtin_amdgcn_exp2f(s[2]));
    r[3] = __fdividef(v[3], 1.0f + __builtin_amdgcn_exp2f(s[3]));
    return r;
}

// async 16B global->LDS (LDS dest wave-uniform base + lane*16)
__device__ __forceinline__ void load16_lds(const unsigned short* g, unsigned short* l) {
    __builtin_amdgcn_global_load_lds(
        (const __attribute__((address_space(1))) unsigned int*)(uintptr_t)g,
        (__attribute__((address_space(3))) unsigned int*)(uintptr_t)l,
        16, 0, 0);
}

// h-dim permutation: C-tile (nt, row r=4q+i) -> h = 32*(nt>>1) + 8*q + 4*(nt&1) + i.
// Chosen so lane (q) holds exactly h in {8q..8q+7} (mod 32): GEMM2's B-fragment
// k = 32c + 8q + j is then IN-LANE -- no cross-lane transpose at all.

// ---------------- merged prep: swz | xtr | misc | zero-agg (one launch) ----------
// blocks 0..1023   : weight convert+swizzle (W1/Wr -> W1r, W2 -> W2s)
// blocks 1024..1279: x transpose (64-row tiles)
// block  1280      : softmax + rbf coeffs (exp2-folded) + rbias
// blocks 1281..1288: LN param packs Pk
// blocks 1289..1352: zero agg (8 MB)
__global__ void __launch_bounds__(256) prep_all(
    const float* __restrict__ att, const float* __restrict__ log_widths,
    const float* __restrict__ centers, const float* __restrict__ br,
    const float* __restrict__ bias,
    const float* __restrict__ b1, const float* __restrict__ g1, const float* __restrict__ be1,
    const float* __restrict__ b2, const float* __restrict__ g2, const float* __restrict__ be2,
    const float* __restrict__ W1, const float* __restrict__ Wr, const float* __restrict__ W2,
    const float* __restrict__ x,
    float* __restrict__ wsoft, float* __restrict__ crw2, float* __restrict__ rbias,
    float* __restrict__ Pk, unsigned short* __restrict__ W1r,
    unsigned short* __restrict__ W2s, float* __restrict__ xT, float* __restrict__ agg)
{
    const int bid = blockIdx.x;
    const int t   = threadIdx.x;
    __shared__ float tile[64][65];   // xtr branch; doubles as ws for misc

    if (bid < 1024) {
        // ---- weight swizzle into MFMA A-frag order ----
        const int gid = bid * 256 + t;
        const int l = gid & 63;
        const int r = l & 15;
        const int sig_base = ((r >> 2) << 3) + (r & 3);   // 8*(r>>2) + (r&3)
        if (gid < 131072) {
            // W1 / Wr: [F][64][128], K=64 -> 2 k-tiles; packed per f (W1 @0, Wr @8192)
            const int id = gid & 65535;
            const float* W = (gid < 65536) ? W1 : Wr;
            const int half = (gid < 65536) ? 0 : 8192;
            const int c  = (id >> 6) & 1;
            const int nt = (id >> 7) & 7;
            const int f  = id >> 10;
            const int hrow = ((nt >> 1) << 5) + ((nt & 1) << 2) + sig_base;
            const float* src = W + ((size_t)(f * 64 + c * 32 + (l >> 4) * 8)) * HD + hrow;
            s16x8 o;
#pragma unroll
            for (int j = 0; j < 8; ++j) o[j] = (short)f2bf(src[(size_t)j * HD]);
            *(s16x8*)(W1r + (size_t)f * 16384 + half + ((size_t)((nt * 2 + c) * 64 + l)) * 8) = o;
        } else {
            // W2: [F][128][128], K=128 -> 4 k-tiles
            const int id = gid - 131072;
            const int c  = (id >> 6) & 3;
            const int nt = (id >> 8) & 7;
            const int f  = id >> 11;
            const int hrow = ((nt >> 1) << 5) + ((nt & 1) << 2) + sig_base;
            const float* src = W2 + ((size_t)(f * 128 + c * 32 + (l >> 4) * 8)) * HD + hrow;
            s16x8 o;
#pragma unroll
            for (int j = 0; j < 8; ++j) o[j] = (short)f2bf(src[(size_t)j * HD]);
            *(s16x8*)(W2s + (size_t)f * 16384 + ((size_t)((nt * 4 + c) * 64 + l)) * 8) = o;
        }
    } else if (bid < 1280) {
        // ---- LDS-tiled x transpose ----
        const int b0 = (bid - 1024) * 64;
        {
            const int row = t & 63, cg = (t >> 6) * 16;
            const float4* src = (const float4*)(x + (size_t)(b0 + row) * FQ + cg);
#pragma unroll
            for (int i = 0; i < 4; ++i) {
                const float4 v = src[i];
                tile[row][cg + i * 4 + 0] = v.x;
                tile[row][cg + i * 4 + 1] = v.y;
                tile[row][cg + i * 4 + 2] = v.z;
                tile[row][cg + i * 4 + 3] = v.w;
            }
        }
        __syncthreads();
        {
            const int f = t >> 2, r0 = (t & 3) * 16;
            float* dst = xT + (size_t)f * BQ + b0 + r0;
#pragma unroll
            for (int i = 0; i < 16; ++i) dst[i] = tile[r0 + i][f];
        }
    } else if (bid == 1280) {
        // ---- softmax(att), rbf coeffs (exp2-folded), rbias ----
        float* ws = &tile[0][0];
        if (t < 64) {
            float v = att[t];
            float m = v;
#pragma unroll
            for (int s = 32; s >= 1; s >>= 1) m = fmaxf(m, __shfl_xor(m, s, 64));
            float e = expf(v - m);
            float ssum = e;
#pragma unroll
            for (int s = 32; s >= 1; s >>= 1) ssum += __shfl_xor(ssum, s, 64);
            const float w = e / ssum;
            ws[t] = w;
            wsoft[t] = w;
        }
        __syncthreads();
        for (int i = t; i < FQ * NBQ; i += 256) {
            float lw = fminf(fmaxf(log_widths[i], -5.0f), 5.0f);
            // rwq = sqrt(0.5*log2e)/width so that rbf = exp2(-(dq*dq))
            const float rwq = 0.84932179f / (expf(lw) + 0.1f);
            ((float2*)crw2)[i] = make_float2(rwq, -centers[i] * rwq);
        }
        if (t < HD) {
            float s = bias[t];
            for (int f = 0; f < FQ; ++f) s += 0.1f * ws[f] * br[f * HD + t];
            rbias[t] = s;
        }
    } else if (bid < 1289) {
        // ---- LN param packs Pk: per (f,hg): [b1,g1,be1,b2,g2,be2] float4s ----
        const int id = (bid - 1281) * 256 + t;   // id = f*32 + hg, < 2048
        float4* dst = (float4*)Pk + (size_t)id * 6;
        dst[0] = ((const float4*)b1)[id];
        dst[1] = ((const float4*)g1)[id];
        dst[2] = ((const float4*)be1)[id];
        dst[3] = ((const float4*)b2)[id];
        dst[4] = ((const float4*)g2)[id];
        dst[5] = ((const float4*)be2)[id];
    } else {
        // ---- zero agg (8 MB): 64 blocks x 256 t x 32 float4 ----
        const int zb = bid - 1289;
        float4* dst = (float4*)agg + (size_t)zb * 8192 + t;
        const float4 z = make_float4(0.f, 0.f, 0.f, 0.f);
#pragma unroll
        for (int i = 0; i < 32; ++i) dst[i * 256] = z;
    }
}

// ---------------- fused MFMA NAM body (swapped-operand, all-register middle) ----
// grid 512 = 4 fgroups x 128 row-tiles. 512 threads = 8 waves, 16 batch cols/wave.
// Round-7: biases folded into MFMA C-init; rbf + gelu exp2-folded (fewer VALU ops).
__global__ void __launch_bounds__(NT, 4) nam_main(
    const float* __restrict__ crw2,
    const float* __restrict__ xT,
    const unsigned short* __restrict__ W1r,
    const unsigned short* __restrict__ W2s,
    const float* __restrict__ Pk,
    const float* __restrict__ wsoft,
    float* __restrict__ agg)
{
    __shared__ __align__(16) unsigned short smem[32768];   // 64 KB: weights / epi tile
    __shared__ __align__(16) float pkbuf[2][768];          // 2 x 3 KB LN packs
    __shared__ __align__(16) float cwbuf[2][128];          // 2 x 512 B rbf coeffs
    unsigned short* bufA = smem;            // 32 KB: W1 + Wr
    unsigned short* bufB = smem + 16384;    // 32 KB: W2

    const int t  = threadIdx.x;
    const int ln = t & 63;
    const int wv = t >> 6;
    const int n  = ln & 15;
    const int q  = ln >> 4;
    const int fb = ln * 8;               // lane frag base (shorts)
    const int fg = blockIdx.x & 3;
    const int rb = blockIdx.x >> 2;
    const int b0 = rb * MT;

    f32x4 acc[8];
#pragma unroll
    for (int nt = 0; nt < 8; ++nt) acc[nt] = f32x4{0.f, 0.f, 0.f, 0.f};

    // ---- prologue: stage f(0) weights + params ----
    {
        const int f0 = fg * FPG + (rb & (FPG - 1));
        const unsigned short* g1r = W1r + (size_t)f0 * 16384;
        const unsigned short* gw2 = W2s + (size_t)f0 * 16384;
#pragma unroll
        for (int i = 0; i < 4; ++i) {
            const int chunk = i * 8 + wv;
            load16_lds(g1r + chunk * 512 + fb, bufA + chunk * 512);
        }
#pragma unroll
        for (int i = 0; i < 4; ++i) {
            const int chunk = i * 8 + wv;
            load16_lds(gw2 + chunk * 512 + fb, bufB + chunk * 512);
        }
        if (wv < 3)
            load16_lds((const unsigned short*)(Pk + (size_t)f0 * 768) + wv * 512 + ln * 8,
                       (unsigned short*)pkbuf[0] + wv * 512);
        if (wv == 3 && q < 2)
            load16_lds((const unsigned short*)(crw2 + (size_t)f0 * 128) + ln * 8,
                       (unsigned short*)cwbuf[0] + ln * 8);
    }

    for (int ff = 0; ff < FPG; ++ff) {
        const int f  = fg * FPG + ((ff + rb) & (FPG - 1));       // decorrelated order
        const int fn = fg * FPG + ((ff + 1 + rb) & (FPG - 1));
        const int p  = ff & 1;
        const float wf   = wsoft[f];
        const float wf01 = 0.1f * wf;

        // x value for this lane's batch col (global scalar; safe before C)
        float xv = xT[(size_t)f * BQ + b0 + wv * 16 + n];
        xv = fminf(fmaxf(xv, -10.0f), 10.0f);

        // C: full drain (vmcnt0) -> bufA/bufB/pkbuf[p]/cwbuf[p] visible.
        __syncthreads();

        // ---- rbf B-fragments: e = exp2(-(dq*dq)), neg is a free src modifier ----
        s16x8 a0, a1;
        {
            const float4* c4 = (const float4*)cwbuf[p];
            unsigned pk[8];
#pragma unroll
            for (int h = 0; h < 2; ++h) {
#pragma unroll
                for (int i = 0; i < 4; ++i) {
                    const float4 cc = c4[h * 16 + q * 4 + i];   // {rwq,ncq, rwq,ncq}
                    const float d0 = fmaf(xv, cc.x, cc.y);
                    const float d1 = fmaf(xv, cc.z, cc.w);
                    const float e0 = __builtin_amdgcn_exp2f(-(d0 * d0));
                    const float e1 = __builtin_amdgcn_exp2f(-(d1 * d1));
                    pk[h * 4 + i] = __builtin_amdgcn_perm(__float_as_uint(e1),
                                                          __float_as_uint(e0), 0x07060302u);
                }
            }
            int4 pa = make_int4(pk[0], pk[1], pk[2], pk[3]);
            int4 pb = make_int4(pk[4], pk[5], pk[6], pk[7]);
            a0 = *(s16x8*)&pa;
            a1 = *(s16x8*)&pb;
        }

        const f32x4* pkf = (const f32x4*)pkbuf[p] + q * 12;

        // ---- GEMM1 (hc, b1 folded into C-init) + GEMMr folded into acc ----
        f32x4 hc[8];
#pragma unroll
        for (int nt = 0; nt < 8; ++nt) {
            const s16x8 w10 = *(const s16x8*)&bufA[(nt * 2 + 0) * 512 + fb];
            const s16x8 w11 = *(const s16x8*)&bufA[(nt * 2 + 1) * 512 + fb];
            f32x4 z = pkf[(nt >> 1) * 48 + (nt & 1) * 6];   // b1 (row-const across n)
            z = __builtin_amdgcn_mfma_f32_16x16x32_bf16(w10, a0, z, 0, 0, 0);
            z = __builtin_amdgcn_mfma_f32_16x16x32_bf16(w11, a1, z, 0, 0, 0);
            hc[nt] = z;
            const s16x8 wr0 = *(const s16x8*)&bufA[8192 + (nt * 2 + 0) * 512 + fb];
            const s16x8 wr1 = *(const s16x8*)&bufA[8192 + (nt * 2 + 1) * 512 + fb];
            f32x4 y = f32x4{0.f, 0.f, 0.f, 0.f};
            y = __builtin_amdgcn_mfma_f32_16x16x32_bf16(wr0, a0, y, 0, 0, 0);
            y = __builtin_amdgcn_mfma_f32_16x16x32_bf16(wr1, a1, y, 0, 0, 0);
            acc[nt] = y * wf01 + acc[nt];   // residual folded now
        }

        // ---- LN1 stats (bias already in hc) ----
        f32x4 sm4 = {0.f, 0.f, 0.f, 0.f}, sq4 = {0.f, 0.f, 0.f, 0.f};
#pragma unroll
        for (int nt = 0; nt < 8; ++nt) {
            const f32x4 v = hc[nt];
            sm4 += v; sq4 += v * v;
        }
        float sm = (sm4[0] + sm4[1]) + (sm4[2] + sm4[3]);
        float sq = (sq4[0] + sq4[1]) + (sq4[2] + sq4[3]);
        sm += __shfl_xor(sm, 16); sm += __shfl_xor(sm, 32);
        sq += __shfl_xor(sq, 16); sq += __shfl_xor(sq, 32);
        const float mu = sm * (1.0f / 128.0f);
        const float rs = rsqrtf(sq * (1.0f / 128.0f) - mu * mu + 1e-5f);

        // E: bufA readers done (all waves past GEMM1); pkbuf[p] still live (dbuf).
        __syncthreads();

        // ---- stage W1+Wr(fn)+Pk(fn)+crw(fn); in flight until next C ----
        if (ff < FPG - 1) {
            const unsigned short* g1r = W1r + (size_t)fn * 16384;
#pragma unroll
            for (int i = 0; i < 4; ++i) {
                const int chunk = i * 8 + wv;
                load16_lds(g1r + chunk * 512 + fb, bufA + chunk * 512);
            }
            if (wv < 3)
                load16_lds((const unsigned short*)(Pk + (size_t)fn * 768) + wv * 512 + ln * 8,
                           (unsigned short*)pkbuf[p ^ 1] + wv * 512);
            if (wv == 3 && q < 2)
                load16_lds((const unsigned short*)(crw2 + (size_t)fn * 128) + ln * 8,
                           (unsigned short*)cwbuf[p ^ 1] + ln * 8);
        }

        // ---- LN1 pass 2 + gelu + pack PAIRWISE into bfr ----
        s16x8 bfr[4];
#pragma unroll
        for (int c = 0; c < 4; ++c) {
            const f32x4 gg0 = pkf[c * 48 + 1];
            const f32x4 bb0 = pkf[c * 48 + 2];
            const f32x4 gg1 = pkf[c * 48 + 6 + 1];
            const f32x4 bb1 = pkf[c * 48 + 6 + 2];
            const f32x4 z0 = gelu4((hc[2 * c]     - mu) * (gg0 * rs) + bb0);
            const f32x4 z1 = gelu4((hc[2 * c + 1] - mu) * (gg1 * rs) + bb1);
            int4 w = make_int4(cvtpk_bf16(z0[0], z0[1]), cvtpk_bf16(z0[2], z0[3]),
                               cvtpk_bf16(z1[0], z1[1]), cvtpk_bf16(z1[2], z1[3]));
            bfr[c] = *(s16x8*)&w;
        }

        // ---- GEMM2 (b2 folded into C-init): A = W2 frags (LDS), B = bfr ----
        f32x4 h2[8];
#pragma unroll
        for (int nt = 0; nt < 8; ++nt) {
            f32x4 z = pkf[(nt >> 1) * 48 + (nt & 1) * 6 + 3];   // b2
#pragma unroll
            for (int c = 0; c < 4; ++c) {
                const s16x8 w2f = *(const s16x8*)&bufB[(nt * 4 + c) * 512 + fb];
                z = __builtin_amdgcn_mfma_f32_16x16x32_bf16(w2f, bfr[c], z, 0, 0, 0);
            }
            h2[nt] = z;
        }

        // H: raw barrier -- bufB readers done; W1r/Pk/cw(fn) DMA deliberately crosses.
        __builtin_amdgcn_sched_barrier(0);
        __builtin_amdgcn_s_barrier();
        __builtin_amdgcn_sched_barrier(0);

        // ---- stage W2(fn) -> bufB; covered by LN2 + next rbf, drained at next C ----
        if (ff < FPG - 1) {
            const unsigned short* gw2 = W2s + (size_t)fn * 16384;
#pragma unroll
            for (int i = 0; i < 4; ++i) {
                const int chunk = i * 8 + wv;
                load16_lds(gw2 + chunk * 512 + fb, bufB + chunk * 512);
            }
        }

        // ---- LN2 stats (bias already in h2), gelu, attention weight into acc ----
        f32x4 tm4 = {0.f, 0.f, 0.f, 0.f}, tq4 = {0.f, 0.f, 0.f, 0.f};
#pragma unroll
        for (int nt = 0; nt < 8; ++nt) {
            const f32x4 v = h2[nt];
            tm4 += v; tq4 += v * v;
        }
        float tm = (tm4[0] + tm4[1]) + (tm4[2] + tm4[3]);
        float tq = (tq4[0] + tq4[1]) + (tq4[2] + tq4[3]);
        tm += __shfl_xor(tm, 16); tm += __shfl_xor(tm, 32);
        tq += __shfl_xor(tq, 16); tq += __shfl_xor(tq, 32);
        const float mu2 = tm * (1.0f / 128.0f);
        const float rs2 = rsqrtf(tq * (1.0f / 128.0f) - mu2 * mu2 + 1e-5f);
#pragma unroll
        for (int nt = 0; nt < 8; ++nt) {
            const f32x4 gg = pkf[(nt >> 1) * 48 + (nt & 1) * 6 + 4];
            const f32x4 bb = pkf[(nt >> 1) * 48 + (nt & 1) * 6 + 5];
            const f32x4 y = (h2[nt] - mu2) * (gg * rs2) + bb;
            acc[nt] = gelu4(y) * wf + acc[nt];
        }
    }

    // ---- epilogue: LDS re-coalesce (128x128 f32 tile, XOR-swizzled) ----
    {
        float* fs = (float*)smem;
        const int r = wv * 16 + n;               // this lane's local batch row
#pragma unroll
        for (int nt = 0; nt < 8; ++nt) {
            const int col  = ((nt >> 1) << 5) + (q << 3) + ((nt & 1) << 2);
            const int byte = r * 512 + col * 4;
            const int sw   = byte ^ ((r & 7) << 4);   // bank-spread, 16B-aligned
            *(f32x4*)((char*)fs + sw) = acc[nt];
        }
        __syncthreads();
        // wave wv drains rows [wv*16, wv*16+16); 64 lanes hit 64 CONSECUTIVE floats
        float* aggp = agg + (size_t)b0 * HD;
#pragma unroll
        for (int rr = 0; rr < 16; ++rr) {
            const int row = wv * 16 + rr;
#pragma unroll
            for (int half = 0; half < 2; ++half) {
                const int byte = row * 512 + half * 256 + ln * 4;
                const int sw   = byte ^ ((row & 7) << 4);
                const float v  = *(const float*)((const char*)fs + sw);
                atomicAdd(aggp + (size_t)row * HD + half * 64 + ln, v);
            }
        }
    }
}

// ---------------- mixture-beta head: one wave per batch row ----------------
__global__ void __launch_bounds__(256) nam_head(
    const float* __restrict__ agg, const float* __restrict__ rbias,
    const float* __restrict__ Wpi, const float* __restrict__ bpi,
    const float* __restrict__ Wa,  const float* __restrict__ ba,
    const float* __restrict__ Wb,  const float* __restrict__ bb,
    float* __restrict__ out)
{
    const int gid  = blockIdx.x * blockDim.x + threadIdx.x;
    const int row  = gid >> 6;
    const int lane = threadIdx.x & 63;
    if (row >= BQ) return;

    const float2 p  = ((const float2*)(agg + (size_t)row * HD))[lane];
    const float2 rb = ((const float2*)rbias)[lane];
    const float ax = p.x + rb.x;
    const float ay = p.y + rb.y;

    const float2* wp = (const float2*)Wpi;
    const float2* wa = (const float2*)Wa;
    const float2* wb = (const float2*)Wb;
    const float2 p01 = wp[lane * 3], p23 = wp[lane * 3 + 1], p45 = wp[lane * 3 + 2];
    const float2 a01 = wa[lane * 3], a23 = wa[lane * 3 + 1], a45 = wa[lane * 3 + 2];
    const float2 b01 = wb[lane * 3], b23 = wb[lane * 3 + 1], b45 = wb[lane * 3 + 2];

    float ppi0 = ax * p01.x + ay * p23.y;
    float ppi1 = ax * p01.y + ay * p45.x;
    float ppi2 = ax * p23.x + ay * p45.y;
    float pa0  = ax * a01.x + ay * a23.y;
    float pa1  = ax * a01.y + ay * a45.x;
    float pa2  = ax * a23.x + ay * a45.y;
    float pb0  = ax * b01.x + ay * b23.y;
    float pb1  = ax * b01.y + ay * b45.x;
    float pb2  = ax * b23.x + ay * b45.y;

#pragma unroll
    for (int s = 32; s >= 1; s >>= 1) {
        ppi0 += __shfl_xor(ppi0, s, 64);
        ppi1 += __shfl_xor(ppi1, s, 64);
        ppi2 += __shfl_xor(ppi2, s, 64);
        pa0  += __shfl_xor(pa0,  s, 64);
        pa1  += __shfl_xor(pa1,  s, 64);
        pa2  += __shfl_xor(pa2,  s, 64);
        pb0  += __shfl_xor(pb0,  s, 64);
        pb1  += __shfl_xor(pb1,  s, 64);
        pb2  += __shfl_xor(pb2,  s, 64);
    }

    if (lane == 0) {
        const float z0 = ppi0 + bpi[0], z1 = ppi1 + bpi[1], z2 = ppi2 + bpi[2];
        const float mz = fmaxf(z0, fmaxf(z1, z2));
        const float e0 = expf(z0 - mz), e1 = expf(z1 - mz), e2 = expf(z2 - mz);
        const float es = e0 + e1 + e2;

        const float al0 = fminf(fmaxf(softplus_stable(pa0 + ba[0]) + 1.01f, 1.01f), 100.0f);
        const float al1 = fminf(fmaxf(softplus_stable(pa1 + ba[1]) + 1.01f, 1.01f), 100.0f);
        const float al2 = fminf(fmaxf(softplus_stable(pa2 + ba[2]) + 1.01f, 1.01f), 100.0f);
        const float bt0 = fminf(fmaxf(softplus_stable(pb0 + bb[0]) + 1.01f, 1.01f), 100.0f);
        const float bt1 = fminf(fmaxf(softplus_stable(pb1 + bb[1]) + 1.01f, 1.01f), 100.0f);
        const float bt2 = fminf(fmaxf(softplus_stable(pb2 + bb[2]) + 1.01f, 1.01f), 100.0f);

        const float pred = (e0 * (al0 / (al0 + bt0))
                          + e1 * (al1 / (al1 + bt1))
                          + e2 * (al2 / (al2 + bt2))) / es;
        out[row] = fminf(fmaxf(pred, 0.001f), 0.999f);
    }
}

extern "C" void kernel_launch(void* const* d_in, const int* in_sizes, int n_in,
                              void* d_out, int out_size, void* d_ws, size_t ws_size,
                              hipStream_t stream) {
    const float* x          = (const float*)d_in[0];
    const float* centers    = (const float*)d_in[1];
    const float* log_widths = (const float*)d_in[2];
    const float* W1   = (const float*)d_in[3];
    const float* b1   = (const float*)d_in[4];
    const float* g1   = (const float*)d_in[5];
    const float* be1  = (const float*)d_in[6];
    const float* W2   = (const float*)d_in[7];
    const float* b2   = (const float*)d_in[8];
    const float* g2   = (const float*)d_in[9];
    const float* be2  = (const float*)d_in[10];
    const float* Wr   = (const float*)d_in[11];
    const float* br   = (const float*)d_in[12];
    const float* att  = (const float*)d_in[13];
    const float* bias = (const float*)d_in[14];
    const float* Wpi  = (const float*)d_in[15];
    const float* bpi  = (const float*)d_in[16];
    const float* Wa   = (const float*)d_in[17];
    const float* ba   = (const float*)d_in[18];
    const float* Wb   = (const float*)d_in[19];
    const float* bb   = (const float*)d_in[20];

    // ---- workspace layout (byte offsets, 16B-aligned) ----
    char* ws = (char*)d_ws;
    float*          wsoft = (float*)(ws + 0);          //   256 B
    float*          rbias = (float*)(ws + 1024);       //   512 B
    float*          crw2  = (float*)(ws + 8192);       //  32 KB (float2[4096])
    float*          Pk    = (float*)(ws + 65536);      // 192 KB used (of 256 KB)
    float*          xT    = (float*)(ws + 327680);     //   4 MB
    unsigned short* W1r   = (unsigned short*)(ws + 4521984);   // 2 MB (W1+Wr per f)
    unsigned short* W2s   = (unsigned short*)(ws + 6619136);   // 2 MB
    float*          agg   = (float*)(ws + 8716288);    //   8 MB

    prep_all<<<1353, 256, 0, stream>>>(att, log_widths, centers, br, bias,
                                       b1, g1, be1, b2, g2, be2,
                                       W1, Wr, W2, x,
                                       wsoft, crw2, rbias, Pk, W1r, W2s, xT, agg);

    nam_main<<<(BQ / MT) * FG, NT, 0, stream>>>(crw2, xT, W1r, W2s, Pk,
                                                wsoft, agg);

    nam_head<<<BQ / 4, 256, 0, stream>>>(agg, rbias, Wpi, bpi, Wa, ba, Wb, bb,
                                         (float*)d_out);
}